// Round 3
// baseline (7867.872 us; speedup 1.0000x reference)
//
#include <hip/hip_runtime.h>
#include <math.h>

#define H 128
typedef unsigned short u16;
typedef unsigned char u8;
typedef unsigned int u32;

static inline int cdiv(long long a, long long b) { return (int)((a + b - 1) / b); }

// ---------------- storage codecs ----------------
struct F16 {
    typedef u16 ST;
    static __device__ inline float dec(u16 u) { union { u16 s; _Float16 h; } c; c.s = u; return (float)c.h; }
    static __device__ inline u16 enc(float f) { union { u16 s; _Float16 h; } c; c.h = (_Float16)f; return c.s; }
    static __device__ inline float4 load4(const ST* p) {
        union { uint2 v; u16 s[4]; } c; c.v = *(const uint2*)p;
        return make_float4(dec(c.s[0]), dec(c.s[1]), dec(c.s[2]), dec(c.s[3]));
    }
    static __device__ inline void store8(ST* p, const float* f) {
        union { uint4 v; u16 s[8]; } c;
#pragma unroll
        for (int j = 0; j < 8; ++j) c.s[j] = enc(f[j]);
        *(uint4*)p = c.v;
    }
};

struct F8 {  // OCP e4m3fn, software codec
    typedef u8 ST;
    static __device__ inline float dec(u8 v) {
        int e = (v >> 3) & 15, m = v & 7;
        float f = (e == 0) ? (float)m * 0.001953125f : ldexpf(1.f + 0.125f * (float)m, e - 7);
        return (v & 0x80) ? -f : f;
    }
    static __device__ inline u8 enc(float x) {
        u8 s = (u8)((__float_as_uint(x) >> 24) & 0x80);
        float ax = fabsf(x);
        if (!(ax < 448.f)) return s | 0x7E;          // clamp; catches NaN too
        if (ax < 0.015625f) {                        // subnormal domain (< 2^-6)
            int m = (int)rintf(ax * 512.f);
            if (m >= 8) return s | 0x08;
            return s | (u8)m;
        }
        int e; float fr = frexpf(ax, &e);            // ax = fr*2^e, fr in [0.5,1)
        int E = e - 1;
        int m = (int)rintf(fr * 16.f - 8.f);         // round mantissa, RNE
        if (m == 8) { m = 0; ++E; }
        if (E > 8) return s | 0x7E;
        return s | (u8)(((E + 7) << 3) | m);
    }
    static __device__ inline float4 load4(const ST* p) {
        union { u32 v; u8 b[4]; } c; c.v = *(const u32*)p;
        return make_float4(dec(c.b[0]), dec(c.b[1]), dec(c.b[2]), dec(c.b[3]));
    }
    static __device__ inline void store8(ST* p, const float* f) {
        union { uint2 v; u8 b[8]; } c;
#pragma unroll
        for (int j = 0; j < 8; ++j) c.b[j] = enc(f[j]);
        *(uint2*)p = c.v;
    }
};

// ---------------- histograms ----------------
__global__ __launch_bounds__(256) void hist2_k(const int* __restrict__ a, const int* __restrict__ b,
                                               int* __restrict__ ca, int* __restrict__ cb, int n) {
    int i = blockIdx.x * 256 + threadIdx.x;
    if (i < n) { atomicAdd(&ca[a[i]], 1); atomicAdd(&cb[b[i]], 1); }
}
__global__ __launch_bounds__(256) void hist1_k(const int* __restrict__ a, int* __restrict__ ca, int n) {
    int i = blockIdx.x * 256 + threadIdx.x;
    if (i < n) atomicAdd(&ca[a[i]], 1);
}
__global__ __launch_bounds__(256) void rs_k(const int* __restrict__ cnt, float* __restrict__ rs, int n) {
    int i = blockIdx.x * 256 + threadIdx.x;
    if (i < n) { int c = cnt[i]; rs[i] = rsqrtf((float)(c < 1 ? 1 : c)); }
}

// ---------------- scan (exclusive) for CSR offsets ----------------
__global__ __launch_bounds__(256) void scan_block_k(const int* __restrict__ in, int* __restrict__ out,
                                                    int* __restrict__ bsum, int n) {
    __shared__ int sh[256];
    int gid = blockIdx.x * 256 + threadIdx.x;
    int v = (gid < n) ? in[gid] : 0;
    sh[threadIdx.x] = v;
    __syncthreads();
    for (int off = 1; off < 256; off <<= 1) {
        int t = (threadIdx.x >= off) ? sh[threadIdx.x - off] : 0;
        __syncthreads();
        sh[threadIdx.x] += t;
        __syncthreads();
    }
    if (gid < n) out[gid] = sh[threadIdx.x] - v;
    if (threadIdx.x == 255) bsum[blockIdx.x] = sh[255];
}

__global__ __launch_bounds__(256) void scan_bsum_k(int* __restrict__ bsum, int nb) {
    __shared__ int sh[256];
    __shared__ int carry;
    if (threadIdx.x == 0) carry = 0;
    __syncthreads();
    for (int base = 0; base < nb; base += 256) {
        int i = base + threadIdx.x;
        int v = (i < nb) ? bsum[i] : 0;
        sh[threadIdx.x] = v;
        __syncthreads();
        for (int off = 1; off < 256; off <<= 1) {
            int t = (threadIdx.x >= off) ? sh[threadIdx.x - off] : 0;
            __syncthreads();
            sh[threadIdx.x] += t;
            __syncthreads();
        }
        if (i < nb) bsum[i] = sh[threadIdx.x] - v + carry;
        __syncthreads();
        if (threadIdx.x == 0) carry += sh[255];
        __syncthreads();
    }
}

__global__ __launch_bounds__(256) void scan_add_k(int* __restrict__ offs, const int* __restrict__ bsum,
                                                  int* __restrict__ cursor, int n, int nnz) {
    int gid = blockIdx.x * 256 + threadIdx.x;
    if (gid < n) {
        int v = offs[gid] + bsum[gid >> 8];
        offs[gid] = v;
        cursor[gid] = v;
    }
    if (gid == 0) offs[n] = nnz;
}

__global__ __launch_bounds__(256) void fill_csr_k(const int* __restrict__ src, const int* __restrict__ dst,
                                                  int* __restrict__ cursor, int* __restrict__ nbr, int nE) {
    int i = blockIdx.x * 256 + threadIdx.x;
    if (i < nE) {
        int p = atomicAdd(&cursor[dst[i]], 1);
        nbr[p] = src[i];
    }
}

// ---------------- feature init ----------------
template <typename C>
__global__ __launch_bounds__(256) void init_h_k(const int* __restrict__ z, const float* __restrict__ emb,
                                                typename C::ST* __restrict__ h, int total) {
    int idx = blockIdx.x * 256 + threadIdx.x;
    if (idx < total) {
        int n = idx >> 7, j = idx & 127;
        h[idx] = C::enc(emb[(size_t)z[n] * H + j]);
    }
}
template <typename C>
__global__ __launch_bounds__(256) void init_e_k(const float* __restrict__ d, const float* __restrict__ epw,
                                                const float* __restrict__ epb, typename C::ST* __restrict__ e, int total) {
    int idx = blockIdx.x * 256 + threadIdx.x;
    if (idx < total) {
        int i = idx >> 7, j = idx & 127;
        e[idx] = C::enc(fmaf(d[i], epw[j], epb[j]));
    }
}

// ---------------- fused CSR pull-aggregation + GEMM + bias + relu ----------------
// block = 256 threads, 64 dest rows. agg tile in LDS (transposed), then 128x128 GEMM.
template <typename C>
__global__ __launch_bounds__(256) void conv_fused_k(
    const typename C::ST* __restrict__ Xin, typename C::ST* __restrict__ Xout,
    const int* __restrict__ offs, const int* __restrict__ nbr,
    const float* __restrict__ rs_out, const float* __restrict__ rs_in,
    const float* __restrict__ W, const float* __restrict__ bias, int M) {
    __shared__ float aggT[H][68];   // [k][row], 16B-aligned rows
    __shared__ float Ws[32][H];     // [k][col] per K-tile

    const int row0 = blockIdx.x * 64;
    const int tid = threadIdx.x;
    const int lane = tid & 31;      // owns cols 4*lane .. 4*lane+3
    const int rgrp = tid >> 5;      // 0..7

    // phase 1: pull-aggregate 64 rows into LDS (fp32), fold both norm scales
    for (int it = 0; it < 8; ++it) {
        int rl = rgrp * 8 + it;
        int gr = row0 + rl;
        float4 a = make_float4(0.f, 0.f, 0.f, 0.f);
        if (gr < M) {
            int beg = offs[gr], end = offs[gr + 1];
            for (int i = beg; i < end; ++i) {
                int s = nbr[i];
                float sc = rs_out[s];
                float4 v = C::load4(Xin + (size_t)s * H + 4 * lane);
                a.x = fmaf(v.x, sc, a.x);
                a.y = fmaf(v.y, sc, a.y);
                a.z = fmaf(v.z, sc, a.z);
                a.w = fmaf(v.w, sc, a.w);
            }
            float ri = rs_in[gr];
            a.x *= ri; a.y *= ri; a.z *= ri; a.w *= ri;
        }
        aggT[4 * lane + 0][rl] = a.x;
        aggT[4 * lane + 1][rl] = a.y;
        aggT[4 * lane + 2][rl] = a.z;
        aggT[4 * lane + 3][rl] = a.w;
    }
    __syncthreads();

    // phase 2: GEMM from LDS
    const int tr4 = (tid >> 4) << 2;  // row base 0..60
    const int c0 = (tid & 15) << 3;   // col base 0..120
    float acc[4][8];
#pragma unroll
    for (int i = 0; i < 4; ++i)
#pragma unroll
        for (int j = 0; j < 8; ++j) acc[i][j] = 0.f;

    for (int kt = 0; kt < H; kt += 32) {
        {
            int c = (tid & 31) << 2;
            int k0 = tid >> 5;
#pragma unroll
            for (int hh = 0; hh < 4; ++hh) {
                int kk = k0 + 8 * hh;
                *(float4*)&Ws[kk][c] = *(const float4*)(W + (size_t)(kt + kk) * H + c);
            }
        }
        __syncthreads();
#pragma unroll
        for (int kk = 0; kk < 32; ++kk) {
            const float4 xv = *(const float4*)&aggT[kt + kk][tr4];
            const float4 wa = *(const float4*)&Ws[kk][c0];
            const float4 wb = *(const float4*)&Ws[kk][c0 + 4];
            const float xs[4] = {xv.x, xv.y, xv.z, xv.w};
            const float wv[8] = {wa.x, wa.y, wa.z, wa.w, wb.x, wb.y, wb.z, wb.w};
#pragma unroll
            for (int i = 0; i < 4; ++i)
#pragma unroll
                for (int j = 0; j < 8; ++j) acc[i][j] = fmaf(xs[i], wv[j], acc[i][j]);
        }
        __syncthreads();
    }

    const float4 ba = *(const float4*)(bias + c0);
    const float4 bb = *(const float4*)(bias + c0 + 4);
    const float bv[8] = {ba.x, ba.y, ba.z, ba.w, bb.x, bb.y, bb.z, bb.w};
#pragma unroll
    for (int i = 0; i < 4; ++i) {
        int gr = row0 + tr4 + i;
        if (gr < M) {
            float o[8];
#pragma unroll
            for (int j = 0; j < 8; ++j) o[j] = fmaxf(acc[i][j] + bv[j], 0.f);
            C::store8(Xout + (size_t)gr * H + c0, o);
        }
    }
}

// ---------------- segment-sum pooling over sorted ids ----------------
template <typename C>
__global__ __launch_bounds__(128) void pool_sorted_k(const typename C::ST* __restrict__ X,
                                                     const int* __restrict__ seg,
                                                     float* __restrict__ out_sum, int M) {
    const int chunk = blockIdx.x * 256;
    const int j = threadIdx.x;
    const int end = min(chunk + 256, M);
    float acc = 0.f;
    int g_cur = -1;
    for (int r = chunk; r < end; ++r) {
        int g = seg[r];
        if (g != g_cur) {
            if (g_cur >= 0) atomicAdd(&out_sum[(size_t)g_cur * H + j], acc);
            acc = 0.f;
            g_cur = g;
        }
        acc += C::dec(X[(size_t)r * H + j]);
    }
    if (g_cur >= 0) atomicAdd(&out_sum[(size_t)g_cur * H + j], acc);
}

// ---------------- readout MLP ----------------
__global__ __launch_bounds__(128) void readout_k(const float* __restrict__ hg, const float* __restrict__ he,
                                                 const int* __restrict__ cn, const int* __restrict__ ce,
                                                 const float* __restrict__ r1w, const float* __restrict__ r1b,
                                                 const float* __restrict__ r2w, const float* __restrict__ r2b,
                                                 float* __restrict__ out) {
    const int b = blockIdx.x;
    const int j = threadIdx.x;
    const float invn = 1.f / fmaxf((float)cn[b], 1.f);
    const float inve = 1.f / fmaxf((float)ce[b], 1.f);
    float acc = r1b[j];
    for (int k = 0; k < H; ++k) acc = fmaf(hg[(size_t)b * H + k] * invn, r1w[(size_t)k * H + j], acc);
    for (int k = 0; k < H; ++k) acc = fmaf(he[(size_t)b * H + k] * inve, r1w[(size_t)(k + H) * H + j], acc);
    float s = acc / (1.f + expf(-acc));
    __shared__ float red[128];
    red[j] = s * r2w[j];
    __syncthreads();
    for (int off = 64; off > 0; off >>= 1) {
        if (j < off) red[j] += red[j + off];
        __syncthreads();
    }
    if (j == 0) out[b] = red[0] + r2b[0];
}

// diagnostic: if workspace too small, report its size (MB) via the output
__global__ void report_k(float* out, int n, float val) {
    int i = blockIdx.x * 64 + threadIdx.x;
    if (i < n) out[i] = val;
}

// ---------------- layout ----------------
struct P {
    char *featA, *featB;
    float *ron, *rin, *roe, *rie;
    int *cnts; size_t cntBytes;
    int *con, *cin, *coe, *cie, *cntn, *cnte;
    int *offs_n, *cur_n, *offs_e, *cur_e, *nbr_n, *nbr_e, *bsum;
    float *pools, *hg, *he;
};

static size_t layout(char* ws, int N, int E, int E2, int B, size_t fe, P& p) {
    size_t off = 0;
    auto al = [&](size_t b) -> char* { char* q = ws + off; off += (b + 255) & ~(size_t)255; return q; };
    p.featA = al((size_t)E * H * fe);
    p.featB = al((size_t)E * H * fe);
    p.ron = (float*)al((size_t)N * 4);
    p.rin = (float*)al((size_t)N * 4);
    p.roe = (float*)al((size_t)E * 4);
    p.rie = (float*)al((size_t)E * 4);
    size_t cntCount = (size_t)2 * N + 2 * E + 2 * B;
    p.cnts = (int*)al(cntCount * 4);
    p.cntBytes = cntCount * 4;
    p.con = p.cnts; p.cin = p.con + N; p.coe = p.cin + N; p.cie = p.coe + E;
    p.cntn = p.cie + E; p.cnte = p.cntn + B;
    p.offs_n = (int*)al(((size_t)N + 1) * 4);
    p.cur_n = (int*)al((size_t)N * 4);
    p.offs_e = (int*)al(((size_t)E + 1) * 4);
    p.cur_e = (int*)al((size_t)E * 4);
    p.nbr_n = (int*)al((size_t)E * 4);
    p.nbr_e = (int*)al((size_t)E2 * 4);
    p.bsum = (int*)al(((size_t)cdiv(E > N ? E : N, 256) + 1) * 4);
    p.pools = (float*)al((size_t)2 * B * H * 4);
    p.hg = p.pools; p.he = p.pools + (size_t)B * H;
    return off;
}

template <typename C>
static void run_all(const P& p, const int* z, const float* d, const int* src, const int* dst,
                    const int* lsrc, const int* ldst, const int* node_graph, const int* edge_graph,
                    const float* emb, const float* epw, const float* epb,
                    const float* gW, const float* gb, const float* lgW, const float* lgb,
                    const float* r1w, const float* r1b, const float* r2w, const float* r2b,
                    float* out, int N, int E, int E2, int B, hipStream_t stream) {
    typedef typename C::ST ST;
    const int L = 3;

    hipMemsetAsync(p.cnts, 0, p.cntBytes, stream);
    hipMemsetAsync(p.pools, 0, (size_t)2 * B * H * 4, stream);

    hist2_k<<<cdiv(E, 256), 256, 0, stream>>>(src, dst, p.con, p.cin, E);
    hist2_k<<<cdiv(E2, 256), 256, 0, stream>>>(lsrc, ldst, p.coe, p.cie, E2);
    hist1_k<<<cdiv(N, 256), 256, 0, stream>>>(node_graph, p.cntn, N);
    hist1_k<<<cdiv(E, 256), 256, 0, stream>>>(edge_graph, p.cnte, E);
    rs_k<<<cdiv(N, 256), 256, 0, stream>>>(p.con, p.ron, N);
    rs_k<<<cdiv(N, 256), 256, 0, stream>>>(p.cin, p.rin, N);
    rs_k<<<cdiv(E, 256), 256, 0, stream>>>(p.coe, p.roe, E);
    rs_k<<<cdiv(E, 256), 256, 0, stream>>>(p.cie, p.rie, E);

    // CSR (by dst) for node graph and line graph
    int nbN = cdiv(N, 256), nbE = cdiv(E, 256);
    scan_block_k<<<nbN, 256, 0, stream>>>(p.cin, p.offs_n, p.bsum, N);
    scan_bsum_k<<<1, 256, 0, stream>>>(p.bsum, nbN);
    scan_add_k<<<nbN, 256, 0, stream>>>(p.offs_n, p.bsum, p.cur_n, N, E);
    fill_csr_k<<<cdiv(E, 256), 256, 0, stream>>>(src, dst, p.cur_n, p.nbr_n, E);

    scan_block_k<<<nbE, 256, 0, stream>>>(p.cie, p.offs_e, p.bsum, E);
    scan_bsum_k<<<1, 256, 0, stream>>>(p.bsum, nbE);
    scan_add_k<<<nbE, 256, 0, stream>>>(p.offs_e, p.bsum, p.cur_e, E, E2);
    fill_csr_k<<<cdiv(E2, 256), 256, 0, stream>>>(lsrc, ldst, p.cur_e, p.nbr_e, E2);

    // node-graph phase
    ST* fA = (ST*)p.featA;
    ST* fB = (ST*)p.featB;
    init_h_k<C><<<cdiv((long long)N * H, 256), 256, 0, stream>>>(z, emb, fA, N * H);
    ST* cur = fA;
    for (int l = 0; l < L; ++l) {
        ST* nxt = (cur == fA) ? fB : fA;
        conv_fused_k<C><<<cdiv(N, 64), 256, 0, stream>>>(cur, nxt, p.offs_n, p.nbr_n, p.ron, p.rin,
                                                         gW + (size_t)l * H * H, gb + (size_t)l * H, N);
        cur = nxt;
    }
    pool_sorted_k<C><<<cdiv(N, 256), 128, 0, stream>>>(cur, node_graph, p.hg, N);

    // line-graph phase
    init_e_k<C><<<cdiv((long long)E * H, 256), 256, 0, stream>>>(d, epw, epb, fA, E * H);
    cur = fA;
    for (int l = 0; l < L; ++l) {
        ST* nxt = (cur == fA) ? fB : fA;
        conv_fused_k<C><<<cdiv(E, 64), 256, 0, stream>>>(cur, nxt, p.offs_e, p.nbr_e, p.roe, p.rie,
                                                         lgW + (size_t)l * H * H, lgb + (size_t)l * H, E);
        cur = nxt;
    }
    pool_sorted_k<C><<<cdiv(E, 256), 128, 0, stream>>>(cur, edge_graph, p.he, E);

    readout_k<<<B, 128, 0, stream>>>(p.hg, p.he, p.cntn, p.cnte, r1w, r1b, r2w, r2b, out);
}

extern "C" void kernel_launch(void* const* d_in, const int* in_sizes, int n_in,
                              void* d_out, int out_size, void* d_ws, size_t ws_size,
                              hipStream_t stream) {
    const int* z          = (const int*)d_in[0];
    const float* d        = (const float*)d_in[1];
    const int* src        = (const int*)d_in[2];
    const int* dst        = (const int*)d_in[3];
    const int* lsrc       = (const int*)d_in[4];
    const int* ldst       = (const int*)d_in[5];
    const int* node_graph = (const int*)d_in[6];
    const int* edge_graph = (const int*)d_in[7];
    const float* emb      = (const float*)d_in[8];
    const float* epw      = (const float*)d_in[9];
    const float* epb      = (const float*)d_in[10];
    const float* gW       = (const float*)d_in[11];
    const float* gb       = (const float*)d_in[12];
    const float* lgW      = (const float*)d_in[13];
    const float* lgb      = (const float*)d_in[14];
    const float* r1w      = (const float*)d_in[15];
    const float* r1b      = (const float*)d_in[16];
    const float* r2w      = (const float*)d_in[17];
    const float* r2b      = (const float*)d_in[18];

    const int N  = in_sizes[0];
    const int E  = in_sizes[2];
    const int E2 = in_sizes[4];
    const int B  = out_size;
    float* out = (float*)d_out;
    char* ws = (char*)d_ws;

    P p;
    size_t need = layout(ws, N, E, E2, B, 2, p);   // fp16 tier (~332 MB)
    if (ws_size >= need) {
        run_all<F16>(p, z, d, src, dst, lsrc, ldst, node_graph, edge_graph, emb, epw, epb,
                     gW, gb, lgW, lgb, r1w, r1b, r2w, r2b, out, N, E, E2, B, stream);
        return;
    }
    need = layout(ws, N, E, E2, B, 1, p);          // fp8 tier (~179 MB)
    if (ws_size >= need) {
        run_all<F8>(p, z, d, src, dst, lsrc, ldst, node_graph, edge_graph, emb, epw, epb,
                    gW, gb, lgW, lgb, r1w, r1b, r2w, r2b, out, N, E, E2, B, stream);
        return;
    }
    // neither fits: report ws_size in MB through the output for diagnosis
    report_k<<<cdiv(B, 64), 64, 0, stream>>>(out, B, (float)(ws_size >> 20));
}

// Round 5
// 1965.535 us; speedup vs baseline: 4.0029x; 4.0029x over previous
//
#include <hip/hip_runtime.h>
#include <math.h>

#define H 128
typedef unsigned short u16;
typedef unsigned char u8;
typedef unsigned int u32;
typedef _Float16 f16;
typedef f16 f16x8 __attribute__((ext_vector_type(8)));
typedef float f32x4 __attribute__((ext_vector_type(4)));

static inline int cdiv(long long a, long long b) { return (int)((a + b - 1) / b); }

// ---------------- fp8 e4m3fn software codec (proven in round 3) ----------------
struct F8 {
    static __device__ inline float dec(u8 v) {
        int e = (v >> 3) & 15, m = v & 7;
        float f = (e == 0) ? (float)m * 0.001953125f : ldexpf(1.f + 0.125f * (float)m, e - 7);
        return (v & 0x80) ? -f : f;
    }
    static __device__ inline u8 enc(float x) {
        u8 s = (u8)((__float_as_uint(x) >> 24) & 0x80);
        float ax = fabsf(x);
        if (!(ax < 448.f)) return s | 0x7E;
        if (ax < 0.015625f) {
            int m = (int)rintf(ax * 512.f);
            if (m >= 8) return s | 0x08;
            return s | (u8)m;
        }
        int e; float fr = frexpf(ax, &e);
        int E = e - 1;
        int m = (int)rintf(fr * 16.f - 8.f);
        if (m == 8) { m = 0; ++E; }
        if (E > 8) return s | 0x7E;
        return s | (u8)(((E + 7) << 3) | m);
    }
    static __device__ inline float4 load4(const u8* p) {
        union { u32 v; u8 b[4]; } c; c.v = *(const u32*)p;
        return make_float4(dec(c.b[0]), dec(c.b[1]), dec(c.b[2]), dec(c.b[3]));
    }
};

static __device__ inline u16 h_bits(float x) {
    union { u16 s; f16 h; } c; c.h = (f16)x; return c.s;
}

// ---------------- degree histograms (wide bins — low contention) ----------------
__global__ __launch_bounds__(256) void hist2_k(const int* __restrict__ a, const int* __restrict__ b,
                                               int* __restrict__ ca, int* __restrict__ cb, int n) {
    int i = blockIdx.x * 256 + threadIdx.x;
    if (i < n) { atomicAdd(&ca[a[i]], 1); atomicAdd(&cb[b[i]], 1); }
}
__global__ __launch_bounds__(256) void rs_k(const int* __restrict__ cnt, float* __restrict__ rs, int n) {
    int i = blockIdx.x * 256 + threadIdx.x;
    if (i < n) { int c = cnt[i]; rs[i] = rsqrtf((float)(c < 1 ? 1 : c)); }
}

// ---------------- segment counts of a SORTED id array via binary search ----------------
__global__ __launch_bounds__(128) void seg_bounds_k(const int* __restrict__ seg, int n, int B,
                                                    int* __restrict__ cnt) {
    __shared__ int bound[129];
    int b = threadIdx.x;
    if (b <= B) {
        int lo = 0, hi = n;
        while (lo < hi) {
            int mid = (lo + hi) >> 1;
            if (seg[mid] < b) lo = mid + 1; else hi = mid;
        }
        bound[b] = lo;
    }
    __syncthreads();
    if (b < B) cnt[b] = bound[b + 1] - bound[b];
}

// ---------------- scan (exclusive) for CSR offsets ----------------
__global__ __launch_bounds__(256) void scan_block_k(const int* __restrict__ in, int* __restrict__ out,
                                                    int* __restrict__ bsum, int n) {
    __shared__ int sh[256];
    int gid = blockIdx.x * 256 + threadIdx.x;
    int v = (gid < n) ? in[gid] : 0;
    sh[threadIdx.x] = v;
    __syncthreads();
    for (int off = 1; off < 256; off <<= 1) {
        int t = (threadIdx.x >= off) ? sh[threadIdx.x - off] : 0;
        __syncthreads();
        sh[threadIdx.x] += t;
        __syncthreads();
    }
    if (gid < n) out[gid] = sh[threadIdx.x] - v;
    if (threadIdx.x == 255) bsum[blockIdx.x] = sh[255];
}

__global__ __launch_bounds__(256) void scan_bsum_k(int* __restrict__ bsum, int nb) {
    __shared__ int sh[256];
    __shared__ int carry;
    if (threadIdx.x == 0) carry = 0;
    __syncthreads();
    for (int base = 0; base < nb; base += 256) {
        int i = base + threadIdx.x;
        int v = (i < nb) ? bsum[i] : 0;
        sh[threadIdx.x] = v;
        __syncthreads();
        for (int off = 1; off < 256; off <<= 1) {
            int t = (threadIdx.x >= off) ? sh[threadIdx.x - off] : 0;
            __syncthreads();
            sh[threadIdx.x] += t;
            __syncthreads();
        }
        if (i < nb) bsum[i] = sh[threadIdx.x] - v + carry;
        __syncthreads();
        if (threadIdx.x == 0) carry += sh[255];
        __syncthreads();
    }
}

__global__ __launch_bounds__(256) void scan_add_k(int* __restrict__ offs, const int* __restrict__ bsum,
                                                  int* __restrict__ cursor, int n, int nnz) {
    int gid = blockIdx.x * 256 + threadIdx.x;
    if (gid < n) {
        int v = offs[gid] + bsum[gid >> 8];
        offs[gid] = v;
        cursor[gid] = v;
    }
    if (gid == 0) offs[n] = nnz;
}

__global__ __launch_bounds__(256) void fill_csr_k(const int* __restrict__ src, const int* __restrict__ dst,
                                                  int* __restrict__ cursor, int* __restrict__ nbr, int nE) {
    int i = blockIdx.x * 256 + threadIdx.x;
    if (i < nE) {
        int p = atomicAdd(&cursor[dst[i]], 1);
        nbr[p] = src[i];
    }
}

// ---------------- feature init (fp8 storage, 4 cols / thread) ----------------
__global__ __launch_bounds__(256) void init_h_k(const int* __restrict__ z, const float* __restrict__ emb,
                                                u8* __restrict__ h, int M) {
    int idx = blockIdx.x * 256 + threadIdx.x;
    if (idx >= M * 32) return;
    int n = idx >> 5, c4 = (idx & 31) << 2;
    const float4 v = *(const float4*)(emb + (size_t)z[n] * H + c4);
    union { u8 b[4]; u32 u; } pk;
    pk.b[0] = F8::enc(v.x); pk.b[1] = F8::enc(v.y); pk.b[2] = F8::enc(v.z); pk.b[3] = F8::enc(v.w);
    *(u32*)(h + (size_t)n * H + c4) = pk.u;
}
__global__ __launch_bounds__(256) void init_e_k(const float* __restrict__ d, const float* __restrict__ epw,
                                                const float* __restrict__ epb, u8* __restrict__ e, int M) {
    int idx = blockIdx.x * 256 + threadIdx.x;
    if (idx >= M * 32) return;
    int i = idx >> 5, c4 = (idx & 31) << 2;
    float dv = d[i];
    const float4 w = *(const float4*)(epw + c4);
    const float4 b = *(const float4*)(epb + c4);
    union { u8 bb[4]; u32 u; } pk;
    pk.bb[0] = F8::enc(fmaf(dv, w.x, b.x)); pk.bb[1] = F8::enc(fmaf(dv, w.y, b.y));
    pk.bb[2] = F8::enc(fmaf(dv, w.z, b.z)); pk.bb[3] = F8::enc(fmaf(dv, w.w, b.w));
    *(u32*)(e + (size_t)i * H + c4) = pk.u;
}

// ---------------- CSR pull-aggregation: agg[r] = rs_in[r] * sum_s rs_out[s]*X[s] ----------------
// one half-wave (32 lanes, 4 cols each) per destination row; zero LDS -> high occupancy
__global__ __launch_bounds__(256) void agg_k(const u8* __restrict__ Xin, f16* __restrict__ agg,
                                             const int* __restrict__ offs, const int* __restrict__ nbr,
                                             const float* __restrict__ rs_out, const float* __restrict__ rs_in,
                                             int M) {
    int gw = (blockIdx.x * 256 + threadIdx.x) >> 5;
    if (gw >= M) return;
    int lane = threadIdx.x & 31;
    int beg = offs[gw], end = offs[gw + 1];
    float a0 = 0.f, a1 = 0.f, a2 = 0.f, a3 = 0.f;
    for (int i = beg; i < end; ++i) {
        int s = nbr[i];
        float sc = rs_out[s];
        float4 v = F8::load4(Xin + (size_t)s * H + 4 * lane);
        a0 = fmaf(v.x, sc, a0); a1 = fmaf(v.y, sc, a1);
        a2 = fmaf(v.z, sc, a2); a3 = fmaf(v.w, sc, a3);
    }
    float ri = rs_in[gw];
    union { u16 s[4]; uint2 v; } pk;
    pk.s[0] = h_bits(a0 * ri); pk.s[1] = h_bits(a1 * ri);
    pk.s[2] = h_bits(a2 * ri); pk.s[3] = h_bits(a3 * ri);
    *(uint2*)(agg + (size_t)gw * H + 4 * lane) = pk.v;
}

// ---------------- MFMA GEMM: out = relu(agg @ W + b) -> fp8, agg:[M,128] f16, W:[128,128] f32 ----------------
// 256 threads = 4 waves; block tile 64 rows x 128 cols; per-wave 16x128 via mfma_f32_16x16x32_f16.
__global__ __launch_bounds__(256) void gemm_mfma_k(const f16* __restrict__ agg, u8* __restrict__ Xout,
                                                   const float* __restrict__ W, const float* __restrict__ bias,
                                                   int M) {
    __shared__ f16 Wt[128][136];   // transposed W: Wt[n][k]; pad 8 halves -> <=2-way bank alias on b128 reads

    // stage W (fp32->fp16, transpose): thread t handles k=t>>1, n in [64*(t&1), +64)
    {
        int k = threadIdx.x >> 1;
        int nh = (threadIdx.x & 1) << 6;
        for (int n4 = 0; n4 < 64; n4 += 4) {
            float4 w4 = *(const float4*)(W + (size_t)k * H + nh + n4);
            Wt[nh + n4 + 0][k] = (f16)w4.x;
            Wt[nh + n4 + 1][k] = (f16)w4.y;
            Wt[nh + n4 + 2][k] = (f16)w4.z;
            Wt[nh + n4 + 3][k] = (f16)w4.w;
        }
    }
    __syncthreads();

    const int wave = threadIdx.x >> 6;
    const int lane = threadIdx.x & 63;
    const int l15 = lane & 15;
    const int quad = lane >> 4;
    const int rowbase = blockIdx.x * 64 + wave * 16;

    // A fragments: A[m=l15][k=quad*8+j], K-tiles of 32
    int arow = rowbase + l15;
    if (arow >= M) arow = M - 1;               // clamp: only affects rows whose stores are masked
    const f16* ap = agg + (size_t)arow * H + quad * 8;
    f16x8 a[4];
#pragma unroll
    for (int kt = 0; kt < 4; ++kt) a[kt] = *(const f16x8*)(ap + kt * 32);

#pragma unroll
    for (int n0 = 0; n0 < 8; ++n0) {
        f32x4 acc = {0.f, 0.f, 0.f, 0.f};
#pragma unroll
        for (int kt = 0; kt < 4; ++kt) {
            f16x8 b = *(const f16x8*)&Wt[n0 * 16 + l15][kt * 32 + quad * 8];
            acc = __builtin_amdgcn_mfma_f32_16x16x32_f16(a[kt], b, acc, 0, 0, 0);
        }
        int col = n0 * 16 + l15;
        float bv = bias[col];
#pragma unroll
        for (int r = 0; r < 4; ++r) {
            int gr = rowbase + quad * 4 + r;   // C/D: col=lane&15, row=quad*4+reg
            if (gr < M) Xout[(size_t)gr * H + col] = F8::enc(fmaxf(acc[r] + bv, 0.f));
        }
    }
}

// ---------------- segment-sum pooling over sorted ids (fp8 in, fp32 atomic out) ----------------
__global__ __launch_bounds__(128) void pool_sorted_k(const u8* __restrict__ X, const int* __restrict__ seg,
                                                     float* __restrict__ out_sum, int M) {
    const int chunk = blockIdx.x * 256;
    const int j = threadIdx.x;
    const int end = min(chunk + 256, M);
    float acc = 0.f;
    int g_cur = -1;
    for (int r = chunk; r < end; ++r) {
        int g = seg[r];
        if (g != g_cur) {
            if (g_cur >= 0) atomicAdd(&out_sum[(size_t)g_cur * H + j], acc);
            acc = 0.f;
            g_cur = g;
        }
        acc += F8::dec(X[(size_t)r * H + j]);
    }
    if (g_cur >= 0) atomicAdd(&out_sum[(size_t)g_cur * H + j], acc);
}

// ---------------- readout MLP ----------------
__global__ __launch_bounds__(128) void readout_k(const float* __restrict__ hg, const float* __restrict__ he,
                                                 const int* __restrict__ cn, const int* __restrict__ ce,
                                                 const float* __restrict__ r1w, const float* __restrict__ r1b,
                                                 const float* __restrict__ r2w, const float* __restrict__ r2b,
                                                 float* __restrict__ out) {
    const int b = blockIdx.x;
    const int j = threadIdx.x;
    const float invn = 1.f / fmaxf((float)cn[b], 1.f);
    const float inve = 1.f / fmaxf((float)ce[b], 1.f);
    float acc = r1b[j];
    for (int k = 0; k < H; ++k) acc = fmaf(hg[(size_t)b * H + k] * invn, r1w[(size_t)k * H + j], acc);
    for (int k = 0; k < H; ++k) acc = fmaf(he[(size_t)b * H + k] * inve, r1w[(size_t)(k + H) * H + j], acc);
    float s = acc / (1.f + expf(-acc));
    __shared__ float red[128];
    red[j] = s * r2w[j];
    __syncthreads();
    for (int off = 64; off > 0; off >>= 1) {
        if (j < off) red[j] += red[j + off];
        __syncthreads();
    }
    if (j == 0) out[b] = red[0] + r2b[0];
}

// diagnostic
__global__ void report_k(float* out, int n, float val) {
    int i = blockIdx.x * 64 + threadIdx.x;
    if (i < n) out[i] = val;
}

extern "C" void kernel_launch(void* const* d_in, const int* in_sizes, int n_in,
                              void* d_out, int out_size, void* d_ws, size_t ws_size,
                              hipStream_t stream) {
    const int* z          = (const int*)d_in[0];
    const float* d        = (const float*)d_in[1];
    const int* src        = (const int*)d_in[2];
    const int* dst        = (const int*)d_in[3];
    const int* lsrc       = (const int*)d_in[4];
    const int* ldst       = (const int*)d_in[5];
    const int* node_graph = (const int*)d_in[6];
    const int* edge_graph = (const int*)d_in[7];
    const float* emb      = (const float*)d_in[8];
    const float* epw      = (const float*)d_in[9];
    const float* epb      = (const float*)d_in[10];
    const float* gW       = (const float*)d_in[11];
    const float* gb       = (const float*)d_in[12];
    const float* lgW      = (const float*)d_in[13];
    const float* lgb      = (const float*)d_in[14];
    const float* r1w      = (const float*)d_in[15];
    const float* r1b      = (const float*)d_in[16];
    const float* r2w      = (const float*)d_in[17];
    const float* r2b      = (const float*)d_in[18];

    const int N  = in_sizes[0];
    const int E  = in_sizes[2];
    const int E2 = in_sizes[4];
    const int B  = out_size;
    const int L  = 3;
    float* out = (float*)d_out;
    char* ws = (char*)d_ws;

    // ---- workspace layout (~256 MB; ws_size = 268 MB measured round 4) ----
    size_t off = 0;
    auto al = [&](size_t b) -> char* { char* q = ws + off; off += (b + 255) & ~(size_t)255; return q; };
    u8*  feat = (u8*)al((size_t)E * H);            //  76.8 MB fp8 features
    f16* agg  = (f16*)al((size_t)E * H * 2);       // 153.6 MB fp16 aggregation
    float* ron = (float*)al((size_t)N * 4);
    float* rin = (float*)al((size_t)N * 4);
    float* roe = (float*)al((size_t)E * 4);
    float* rie = (float*)al((size_t)E * 4);
    size_t cntCount = (size_t)2 * N + 2 * E + 2 * B;
    int* cnts = (int*)al(cntCount * 4);
    size_t cntBytes = ((size_t)2 * N + 2 * E) * 4;
    int* con = cnts; int* cin_ = con + N; int* coe = cin_ + N; int* cie = coe + E;
    int* cntn = cie + E; int* cnte = cntn + B;
    int* offs_n = (int*)al(((size_t)N + 1) * 4);
    int* cur_n  = (int*)al((size_t)N * 4);
    int* offs_e = (int*)al(((size_t)E + 1) * 4);
    int* cur_e  = (int*)al((size_t)E * 4);
    int* nbr_n  = (int*)al((size_t)E * 4);
    int* nbr_e  = (int*)al((size_t)E2 * 4);
    int* bsum   = (int*)al(((size_t)cdiv(E > N ? E : N, 256) + 1) * 4);
    float* pools = (float*)al((size_t)2 * B * H * 4);
    float* hg = pools;
    float* he = pools + (size_t)B * H;

    if (off > ws_size) {   // doesn't fit: report budget in MB for diagnosis
        report_k<<<cdiv(B, 64), 64, 0, stream>>>(out, B, (float)(ws_size >> 20));
        return;
    }

    hipMemsetAsync(cnts, 0, cntBytes, stream);
    hipMemsetAsync(pools, 0, (size_t)2 * B * H * 4, stream);

    // degrees + graph-segment counts
    hist2_k<<<cdiv(E, 256), 256, 0, stream>>>(src, dst, con, cin_, E);
    hist2_k<<<cdiv(E2, 256), 256, 0, stream>>>(lsrc, ldst, coe, cie, E2);
    seg_bounds_k<<<1, 128, 0, stream>>>(node_graph, N, B, cntn);
    seg_bounds_k<<<1, 128, 0, stream>>>(edge_graph, E, B, cnte);
    rs_k<<<cdiv(N, 256), 256, 0, stream>>>(con, ron, N);
    rs_k<<<cdiv(N, 256), 256, 0, stream>>>(cin_, rin, N);
    rs_k<<<cdiv(E, 256), 256, 0, stream>>>(coe, roe, E);
    rs_k<<<cdiv(E, 256), 256, 0, stream>>>(cie, rie, E);

    // CSR (by dst) for both graphs
    int nbN = cdiv(N, 256), nbE = cdiv(E, 256);
    scan_block_k<<<nbN, 256, 0, stream>>>(cin_, offs_n, bsum, N);
    scan_bsum_k<<<1, 256, 0, stream>>>(bsum, nbN);
    scan_add_k<<<nbN, 256, 0, stream>>>(offs_n, bsum, cur_n, N, E);
    fill_csr_k<<<cdiv(E, 256), 256, 0, stream>>>(src, dst, cur_n, nbr_n, E);

    scan_block_k<<<nbE, 256, 0, stream>>>(cie, offs_e, bsum, E);
    scan_bsum_k<<<1, 256, 0, stream>>>(bsum, nbE);
    scan_add_k<<<nbE, 256, 0, stream>>>(offs_e, bsum, cur_e, E, E2);
    fill_csr_k<<<cdiv(E2, 256), 256, 0, stream>>>(lsrc, ldst, cur_e, nbr_e, E2);

    // node-graph phase
    init_h_k<<<cdiv((long long)N * 32, 256), 256, 0, stream>>>(z, emb, feat, N);
    for (int l = 0; l < L; ++l) {
        agg_k<<<cdiv((long long)N * 32, 256), 256, 0, stream>>>(feat, agg, offs_n, nbr_n, ron, rin, N);
        gemm_mfma_k<<<cdiv(N, 64), 256, 0, stream>>>(agg, feat, gW + (size_t)l * H * H, gb + (size_t)l * H, N);
    }
    pool_sorted_k<<<cdiv(N, 256), 128, 0, stream>>>(feat, node_graph, hg, N);

    // line-graph phase (reuses feat/agg)
    init_e_k<<<cdiv((long long)E * 32, 256), 256, 0, stream>>>(d, epw, epb, feat, E);
    for (int l = 0; l < L; ++l) {
        agg_k<<<cdiv((long long)E * 32, 256), 256, 0, stream>>>(feat, agg, offs_e, nbr_e, roe, rie, E);
        gemm_mfma_k<<<cdiv(E, 64), 256, 0, stream>>>(agg, feat, lgW + (size_t)l * H * H, lgb + (size_t)l * H, E);
    }
    pool_sorted_k<<<cdiv(E, 256), 128, 0, stream>>>(feat, edge_graph, he, E);

    readout_k<<<B, 128, 0, stream>>>(hg, he, cntn, cnte, r1w, r1b, r2w, r2b, out);
}

// Round 6
// 1833.305 us; speedup vs baseline: 4.2916x; 1.0721x over previous
//
#include <hip/hip_runtime.h>
#include <math.h>

#define H 128
typedef unsigned short u16;
typedef unsigned char u8;
typedef unsigned int u32;
typedef _Float16 f16;
typedef f16 f16x8 __attribute__((ext_vector_type(8)));
typedef float f32x4 __attribute__((ext_vector_type(4)));
typedef float f32x2 __attribute__((ext_vector_type(2)));

#if __has_builtin(__builtin_amdgcn_cvt_pk_fp8_f32)
#define HW8 1
#else
#define HW8 0
#endif

static inline int cdiv(long long a, long long b) { return (int)((a + b - 1) / b); }

// ---------------- fp8 e4m3fn software codec (fallback + reference) ----------------
struct F8 {
    static __device__ inline float dec(u8 v) {
        int e = (v >> 3) & 15, m = v & 7;
        float f = (e == 0) ? (float)m * 0.001953125f : ldexpf(1.f + 0.125f * (float)m, e - 7);
        return (v & 0x80) ? -f : f;
    }
    static __device__ inline u8 enc(float x) {
        u8 s = (u8)((__float_as_uint(x) >> 24) & 0x80);
        float ax = fabsf(x);
        if (!(ax < 448.f)) return s | 0x7E;
        if (ax < 0.015625f) {
            int m = (int)rintf(ax * 512.f);
            if (m >= 8) return s | 0x08;
            return s | (u8)m;
        }
        int e; float fr = frexpf(ax, &e);
        int E = e - 1;
        int m = (int)rintf(fr * 16.f - 8.f);
        if (m == 8) { m = 0; ++E; }
        if (E > 8) return s | 0x7E;
        return s | (u8)(((E + 7) << 3) | m);
    }
};

// pack 4 floats -> 4 fp8 bytes
static __device__ inline u32 enc4(float x0, float x1, float x2, float x3) {
#if HW8
    u32 w = __builtin_amdgcn_cvt_pk_fp8_f32(x0, x1, 0, false);
    w = __builtin_amdgcn_cvt_pk_fp8_f32(x2, x3, w, true);
    return w;
#else
    union { u8 b[4]; u32 u; } p;
    p.b[0] = F8::enc(x0); p.b[1] = F8::enc(x1); p.b[2] = F8::enc(x2); p.b[3] = F8::enc(x3);
    return p.u;
#endif
}
// unpack 4 fp8 bytes -> 4 floats
static __device__ inline float4 dec4(u32 v) {
#if HW8
    f32x2 lo = __builtin_amdgcn_cvt_pk_f32_fp8(v, false);
    f32x2 hi = __builtin_amdgcn_cvt_pk_f32_fp8(v, true);
    return make_float4(lo.x, lo.y, hi.x, hi.y);
#else
    union { u32 u; u8 b[4]; } c; c.u = v;
    return make_float4(F8::dec(c.b[0]), F8::dec(c.b[1]), F8::dec(c.b[2]), F8::dec(c.b[3]));
#endif
}
static __device__ inline float dec1(u8 b) {
#if HW8
    return __builtin_amdgcn_cvt_f32_fp8((int)b, 0);
#else
    return F8::dec(b);
#endif
}

static __device__ inline u16 h_bits(float x) {
    union { u16 s; f16 h; } c; c.h = (f16)x; return c.s;
}

// ---------------- degree histograms ----------------
__global__ __launch_bounds__(256) void hist2_k(const int* __restrict__ a, const int* __restrict__ b,
                                               int* __restrict__ ca, int* __restrict__ cb, int n) {
    int i = blockIdx.x * 256 + threadIdx.x;
    if (i < n) { atomicAdd(&ca[a[i]], 1); atomicAdd(&cb[b[i]], 1); }
}
__global__ __launch_bounds__(256) void rs_k(const int* __restrict__ cnt, float* __restrict__ rs, int n) {
    int i = blockIdx.x * 256 + threadIdx.x;
    if (i < n) { int c = cnt[i]; rs[i] = rsqrtf((float)(c < 1 ? 1 : c)); }
}

// ---------------- segment counts of a SORTED id array ----------------
__global__ __launch_bounds__(128) void seg_bounds_k(const int* __restrict__ seg, int n, int B,
                                                    int* __restrict__ cnt) {
    __shared__ int bound[129];
    int b = threadIdx.x;
    if (b <= B) {
        int lo = 0, hi = n;
        while (lo < hi) {
            int mid = (lo + hi) >> 1;
            if (seg[mid] < b) lo = mid + 1; else hi = mid;
        }
        bound[b] = lo;
    }
    __syncthreads();
    if (b < B) cnt[b] = bound[b + 1] - bound[b];
}

// ---------------- scan (exclusive) for CSR offsets ----------------
__global__ __launch_bounds__(256) void scan_block_k(const int* __restrict__ in, int* __restrict__ out,
                                                    int* __restrict__ bsum, int n) {
    __shared__ int sh[256];
    int gid = blockIdx.x * 256 + threadIdx.x;
    int v = (gid < n) ? in[gid] : 0;
    sh[threadIdx.x] = v;
    __syncthreads();
    for (int off = 1; off < 256; off <<= 1) {
        int t = (threadIdx.x >= off) ? sh[threadIdx.x - off] : 0;
        __syncthreads();
        sh[threadIdx.x] += t;
        __syncthreads();
    }
    if (gid < n) out[gid] = sh[threadIdx.x] - v;
    if (threadIdx.x == 255) bsum[blockIdx.x] = sh[255];
}

__global__ __launch_bounds__(256) void scan_bsum_k(int* __restrict__ bsum, int nb) {
    __shared__ int sh[256];
    __shared__ int carry;
    if (threadIdx.x == 0) carry = 0;
    __syncthreads();
    for (int base = 0; base < nb; base += 256) {
        int i = base + threadIdx.x;
        int v = (i < nb) ? bsum[i] : 0;
        sh[threadIdx.x] = v;
        __syncthreads();
        for (int off = 1; off < 256; off <<= 1) {
            int t = (threadIdx.x >= off) ? sh[threadIdx.x - off] : 0;
            __syncthreads();
            sh[threadIdx.x] += t;
            __syncthreads();
        }
        if (i < nb) bsum[i] = sh[threadIdx.x] - v + carry;
        __syncthreads();
        if (threadIdx.x == 0) carry += sh[255];
        __syncthreads();
    }
}

__global__ __launch_bounds__(256) void scan_add_k(int* __restrict__ offs, const int* __restrict__ bsum,
                                                  int* __restrict__ cursor, int n, int nnz) {
    int gid = blockIdx.x * 256 + threadIdx.x;
    if (gid < n) {
        int v = offs[gid] + bsum[gid >> 8];
        offs[gid] = v;
        cursor[gid] = v;
    }
    if (gid == 0) offs[n] = nnz;
}

__global__ __launch_bounds__(256) void fill_csr_k(const int* __restrict__ src, const int* __restrict__ dst,
                                                  int* __restrict__ cursor, int* __restrict__ nbr, int nE) {
    int i = blockIdx.x * 256 + threadIdx.x;
    if (i < nE) {
        int p = atomicAdd(&cursor[dst[i]], 1);
        nbr[p] = src[i];
    }
}

// ---------------- weight prep: Wt[n][k] = (f16) W[k][n] ----------------
__global__ __launch_bounds__(256) void prep_w_k(const float* __restrict__ W, f16* __restrict__ Wt) {
    int idx = blockIdx.x * 256 + threadIdx.x;   // 16384 threads
    int k = idx >> 7, n = idx & 127;
    Wt[(size_t)n * H + k] = (f16)W[(size_t)k * H + n];
}

// ---------------- feature init (fp8, pre-scaled by rs_out) ----------------
__global__ __launch_bounds__(256) void init_h_k(const int* __restrict__ z, const float* __restrict__ emb,
                                                const float* __restrict__ rs, u8* __restrict__ h, int M) {
    int idx = blockIdx.x * 256 + threadIdx.x;
    if (idx >= M * 32) return;
    int n = idx >> 5, c4 = (idx & 31) << 2;
    float sc = rs[n];
    const float4 v = *(const float4*)(emb + (size_t)z[n] * H + c4);
    *(u32*)(h + (size_t)n * H + c4) = enc4(v.x * sc, v.y * sc, v.z * sc, v.w * sc);
}
__global__ __launch_bounds__(256) void init_e_k(const float* __restrict__ d, const float* __restrict__ epw,
                                                const float* __restrict__ epb, const float* __restrict__ rs,
                                                u8* __restrict__ e, int M) {
    int idx = blockIdx.x * 256 + threadIdx.x;
    if (idx >= M * 32) return;
    int i = idx >> 5, c4 = (idx & 31) << 2;
    float dv = d[i], sc = rs[i];
    const float4 w = *(const float4*)(epw + c4);
    const float4 b = *(const float4*)(epb + c4);
    *(u32*)(e + (size_t)i * H + c4) = enc4(fmaf(dv, w.x, b.x) * sc, fmaf(dv, w.y, b.y) * sc,
                                           fmaf(dv, w.z, b.z) * sc, fmaf(dv, w.w, b.w) * sc);
}

// ---------------- CSR pull-aggregation: agg[r] = rs_in[r] * sum_s X[s]  (X pre-scaled) ----------------
// one half-wave (32 lanes, 4 cols each) per destination row; zero LDS
__global__ __launch_bounds__(256) void agg_k(const u8* __restrict__ Xin, f16* __restrict__ agg,
                                             const int* __restrict__ offs, const int* __restrict__ nbr,
                                             const float* __restrict__ rs_in, int M) {
    int gw = (blockIdx.x * 256 + threadIdx.x) >> 5;
    if (gw >= M) return;
    int lane = threadIdx.x & 31;
    int beg = offs[gw], end = offs[gw + 1];
    float a0 = 0.f, a1 = 0.f, a2 = 0.f, a3 = 0.f;
    for (int i = beg; i < end; ++i) {
        int s = nbr[i];
        float4 v = dec4(*(const u32*)(Xin + (size_t)s * H + 4 * lane));
        a0 += v.x; a1 += v.y; a2 += v.z; a3 += v.w;
    }
    float ri = rs_in[gw];
    union { u16 s[4]; uint2 v; } pk;
    pk.s[0] = h_bits(a0 * ri); pk.s[1] = h_bits(a1 * ri);
    pk.s[2] = h_bits(a2 * ri); pk.s[3] = h_bits(a3 * ri);
    *(uint2*)(agg + (size_t)gw * H + 4 * lane) = pk.v;
}

// ---------------- MFMA GEMM: out = relu(agg @ W + b) [* rs_out] -> fp8 ----------------
// no LDS, no barriers; 4 waves/block, wave = 16 rows x 128 cols; B-frags from global Wt (L1-hot)
__global__ __launch_bounds__(256) void gemm_mfma_k(const f16* __restrict__ agg, u8* __restrict__ Xout,
                                                   const f16* __restrict__ Wt, const float* __restrict__ bias,
                                                   const float* __restrict__ scale_out, int M) {
    const int wave = threadIdx.x >> 6;
    const int lane = threadIdx.x & 63;
    const int l15 = lane & 15;
    const int quad = lane >> 4;
    const int rowbase = blockIdx.x * 64 + wave * 16;
    if (rowbase >= M) return;

    int arow = rowbase + l15;
    if (arow >= M) arow = M - 1;               // clamp: stores are masked
    const f16* ap = agg + (size_t)arow * H + quad * 8;
    f16x8 a[4];
#pragma unroll
    for (int kt = 0; kt < 4; ++kt) a[kt] = *(const f16x8*)(ap + kt * 32);

    // row scales for this lane's 4 output rows (C/D: col=lane&15, row=quad*4+reg)
    float rsc[4];
#pragma unroll
    for (int r = 0; r < 4; ++r) {
        int gr = rowbase + quad * 4 + r;
        rsc[r] = (scale_out && gr < M) ? scale_out[gr] : 1.f;
    }

#pragma unroll
    for (int n0 = 0; n0 < 8; ++n0) {
        f32x4 acc = {0.f, 0.f, 0.f, 0.f};
        const f16* bp = Wt + (size_t)(n0 * 16 + l15) * H + quad * 8;
#pragma unroll
        for (int kt = 0; kt < 4; ++kt) {
            f16x8 b = *(const f16x8*)(bp + kt * 32);
            acc = __builtin_amdgcn_mfma_f32_16x16x32_f16(a[kt], b, acc, 0, 0, 0);
        }
        int col = n0 * 16 + l15;
        float bv = bias[col];
        float o[4];
#pragma unroll
        for (int r = 0; r < 4; ++r) o[r] = fmaxf(acc[r] + bv, 0.f) * rsc[r];
        u32 w = enc4(o[0], o[1], o[2], o[3]);
#pragma unroll
        for (int r = 0; r < 4; ++r) {
            int gr = rowbase + quad * 4 + r;
            if (gr < M) Xout[(size_t)gr * H + col] = (u8)(w >> (8 * r));
        }
    }
}

// ---------------- segment-sum pooling over sorted ids ----------------
__global__ __launch_bounds__(128) void pool_sorted_k(const u8* __restrict__ X, const int* __restrict__ seg,
                                                     float* __restrict__ out_sum, int M) {
    const int chunk = blockIdx.x * 256;
    const int j = threadIdx.x;
    const int end = min(chunk + 256, M);
    float acc = 0.f;
    int g_cur = -1;
    for (int r = chunk; r < end; ++r) {
        int g = seg[r];
        if (g != g_cur) {
            if (g_cur >= 0) atomicAdd(&out_sum[(size_t)g_cur * H + j], acc);
            acc = 0.f;
            g_cur = g;
        }
        acc += dec1(X[(size_t)r * H + j]);
    }
    if (g_cur >= 0) atomicAdd(&out_sum[(size_t)g_cur * H + j], acc);
}

// ---------------- readout MLP ----------------
__global__ __launch_bounds__(128) void readout_k(const float* __restrict__ hg, const float* __restrict__ he,
                                                 const int* __restrict__ cn, const int* __restrict__ ce,
                                                 const float* __restrict__ r1w, const float* __restrict__ r1b,
                                                 const float* __restrict__ r2w, const float* __restrict__ r2b,
                                                 float* __restrict__ out) {
    const int b = blockIdx.x;
    const int j = threadIdx.x;
    const float invn = 1.f / fmaxf((float)cn[b], 1.f);
    const float inve = 1.f / fmaxf((float)ce[b], 1.f);
    float acc = r1b[j];
    for (int k = 0; k < H; ++k) acc = fmaf(hg[(size_t)b * H + k] * invn, r1w[(size_t)k * H + j], acc);
    for (int k = 0; k < H; ++k) acc = fmaf(he[(size_t)b * H + k] * inve, r1w[(size_t)(k + H) * H + j], acc);
    float s = acc / (1.f + expf(-acc));
    __shared__ float red[128];
    red[j] = s * r2w[j];
    __syncthreads();
    for (int off = 64; off > 0; off >>= 1) {
        if (j < off) red[j] += red[j + off];
        __syncthreads();
    }
    if (j == 0) out[b] = red[0] + r2b[0];
}

// diagnostic
__global__ void report_k(float* out, int n, float val) {
    int i = blockIdx.x * 64 + threadIdx.x;
    if (i < n) out[i] = val;
}

extern "C" void kernel_launch(void* const* d_in, const int* in_sizes, int n_in,
                              void* d_out, int out_size, void* d_ws, size_t ws_size,
                              hipStream_t stream) {
    const int* z          = (const int*)d_in[0];
    const float* d        = (const float*)d_in[1];
    const int* src        = (const int*)d_in[2];
    const int* dst        = (const int*)d_in[3];
    const int* lsrc       = (const int*)d_in[4];
    const int* ldst       = (const int*)d_in[5];
    const int* node_graph = (const int*)d_in[6];
    const int* edge_graph = (const int*)d_in[7];
    const float* emb      = (const float*)d_in[8];
    const float* epw      = (const float*)d_in[9];
    const float* epb      = (const float*)d_in[10];
    const float* gW       = (const float*)d_in[11];
    const float* gb       = (const float*)d_in[12];
    const float* lgW      = (const float*)d_in[13];
    const float* lgb      = (const float*)d_in[14];
    const float* r1w      = (const float*)d_in[15];
    const float* r1b      = (const float*)d_in[16];
    const float* r2w      = (const float*)d_in[17];
    const float* r2b      = (const float*)d_in[18];

    const int N  = in_sizes[0];
    const int E  = in_sizes[2];
    const int E2 = in_sizes[4];
    const int B  = out_size;
    const int L  = 3;
    float* out = (float*)d_out;
    char* ws = (char*)d_ws;

    // ---- workspace layout (~256 MB; ws_size = 268 MB measured round 4) ----
    size_t off = 0;
    auto al = [&](size_t b) -> char* { char* q = ws + off; off += (b + 255) & ~(size_t)255; return q; };
    u8*  feat = (u8*)al((size_t)E * H);            //  76.8 MB fp8 features (pre-scaled by rs_out)
    f16* agg  = (f16*)al((size_t)E * H * 2);       // 153.6 MB fp16 aggregation
    f16* wt   = (f16*)al((size_t)2 * L * H * H * 2); // 6 transposed fp16 weight mats
    float* ron = (float*)al((size_t)N * 4);
    float* rin = (float*)al((size_t)N * 4);
    float* roe = (float*)al((size_t)E * 4);
    float* rie = (float*)al((size_t)E * 4);
    size_t cntCount = (size_t)2 * N + 2 * E + 2 * B;
    int* cnts = (int*)al(cntCount * 4);
    size_t cntBytes = ((size_t)2 * N + 2 * E) * 4;
    int* con = cnts; int* cin_ = con + N; int* coe = cin_ + N; int* cie = coe + E;
    int* cntn = cie + E; int* cnte = cntn + B;
    int* offs_n = (int*)al(((size_t)N + 1) * 4);
    int* cur_n  = (int*)al((size_t)N * 4);
    int* offs_e = (int*)al(((size_t)E + 1) * 4);
    int* cur_e  = (int*)al((size_t)E * 4);
    int* nbr_n  = (int*)al((size_t)E * 4);
    int* nbr_e  = (int*)al((size_t)E2 * 4);
    int* bsum   = (int*)al(((size_t)cdiv(E > N ? E : N, 256) + 1) * 4);
    float* pools = (float*)al((size_t)2 * B * H * 4);
    float* hg = pools;
    float* he = pools + (size_t)B * H;

    if (off > ws_size) {
        report_k<<<cdiv(B, 64), 64, 0, stream>>>(out, B, (float)(ws_size >> 20));
        return;
    }

    hipMemsetAsync(cnts, 0, cntBytes, stream);
    hipMemsetAsync(pools, 0, (size_t)2 * B * H * 4, stream);

    // weight prep (6 layers)
    for (int l = 0; l < L; ++l) {
        prep_w_k<<<64, 256, 0, stream>>>(gW + (size_t)l * H * H, wt + (size_t)l * H * H);
        prep_w_k<<<64, 256, 0, stream>>>(lgW + (size_t)l * H * H, wt + (size_t)(L + l) * H * H);
    }

    // degrees + graph-segment counts
    hist2_k<<<cdiv(E, 256), 256, 0, stream>>>(src, dst, con, cin_, E);
    hist2_k<<<cdiv(E2, 256), 256, 0, stream>>>(lsrc, ldst, coe, cie, E2);
    seg_bounds_k<<<1, 128, 0, stream>>>(node_graph, N, B, cntn);
    seg_bounds_k<<<1, 128, 0, stream>>>(edge_graph, E, B, cnte);
    rs_k<<<cdiv(N, 256), 256, 0, stream>>>(con, ron, N);
    rs_k<<<cdiv(N, 256), 256, 0, stream>>>(cin_, rin, N);
    rs_k<<<cdiv(E, 256), 256, 0, stream>>>(coe, roe, E);
    rs_k<<<cdiv(E, 256), 256, 0, stream>>>(cie, rie, E);

    // CSR (by dst) for both graphs
    int nbN = cdiv(N, 256), nbE = cdiv(E, 256);
    scan_block_k<<<nbN, 256, 0, stream>>>(cin_, offs_n, bsum, N);
    scan_bsum_k<<<1, 256, 0, stream>>>(bsum, nbN);
    scan_add_k<<<nbN, 256, 0, stream>>>(offs_n, bsum, cur_n, N, E);
    fill_csr_k<<<cdiv(E, 256), 256, 0, stream>>>(src, dst, cur_n, nbr_n, E);

    scan_block_k<<<nbE, 256, 0, stream>>>(cie, offs_e, bsum, E);
    scan_bsum_k<<<1, 256, 0, stream>>>(bsum, nbE);
    scan_add_k<<<nbE, 256, 0, stream>>>(offs_e, bsum, cur_e, E, E2);
    fill_csr_k<<<cdiv(E2, 256), 256, 0, stream>>>(lsrc, ldst, cur_e, nbr_e, E2);

    // node-graph phase (feat pre-scaled by ron except after final layer)
    init_h_k<<<cdiv((long long)N * 32, 256), 256, 0, stream>>>(z, emb, ron, feat, N);
    for (int l = 0; l < L; ++l) {
        agg_k<<<cdiv((long long)N * 32, 256), 256, 0, stream>>>(feat, agg, offs_n, nbr_n, rin, N);
        gemm_mfma_k<<<cdiv(N, 64), 256, 0, stream>>>(agg, feat, wt + (size_t)l * H * H,
                                                     gb + (size_t)l * H, (l < L - 1) ? ron : nullptr, N);
    }
    pool_sorted_k<<<cdiv(N, 256), 128, 0, stream>>>(feat, node_graph, hg, N);

    // line-graph phase
    init_e_k<<<cdiv((long long)E * 32, 256), 256, 0, stream>>>(d, epw, epb, roe, feat, E);
    for (int l = 0; l < L; ++l) {
        agg_k<<<cdiv((long long)E * 32, 256), 256, 0, stream>>>(feat, agg, offs_e, nbr_e, rie, E);
        gemm_mfma_k<<<cdiv(E, 64), 256, 0, stream>>>(agg, feat, wt + (size_t)(L + l) * H * H,
                                                     lgb + (size_t)l * H, (l < L - 1) ? roe : nullptr, E);
    }
    pool_sorted_k<<<cdiv(E, 256), 128, 0, stream>>>(feat, edge_graph, he, E);

    readout_k<<<B, 128, 0, stream>>>(hg, he, cntn, cnte, r1w, r1b, r2w, r2b, out);
}

// Round 7
// 1616.496 us; speedup vs baseline: 4.8672x; 1.1341x over previous
//
#include <hip/hip_runtime.h>
#include <math.h>

#define H 128
typedef unsigned short u16;
typedef unsigned char u8;
typedef unsigned int u32;
typedef _Float16 f16;
typedef f16 f16x8 __attribute__((ext_vector_type(8)));
typedef float f32x4 __attribute__((ext_vector_type(4)));
typedef float f32x2 __attribute__((ext_vector_type(2)));

#if __has_builtin(__builtin_amdgcn_cvt_pk_fp8_f32)
#define HW8 1
#else
#define HW8 0
#endif

static inline int cdiv(long long a, long long b) { return (int)((a + b - 1) / b); }

// ---------------- fp8 e4m3fn software codec (fallback) ----------------
struct F8 {
    static __device__ inline float dec(u8 v) {
        int e = (v >> 3) & 15, m = v & 7;
        float f = (e == 0) ? (float)m * 0.001953125f : ldexpf(1.f + 0.125f * (float)m, e - 7);
        return (v & 0x80) ? -f : f;
    }
    static __device__ inline u8 enc(float x) {
        u8 s = (u8)((__float_as_uint(x) >> 24) & 0x80);
        float ax = fabsf(x);
        if (!(ax < 448.f)) return s | 0x7E;
        if (ax < 0.015625f) {
            int m = (int)rintf(ax * 512.f);
            if (m >= 8) return s | 0x08;
            return s | (u8)m;
        }
        int e; float fr = frexpf(ax, &e);
        int E = e - 1;
        int m = (int)rintf(fr * 16.f - 8.f);
        if (m == 8) { m = 0; ++E; }
        if (E > 8) return s | 0x7E;
        return s | (u8)(((E + 7) << 3) | m);
    }
};

static __device__ inline u32 enc4(float x0, float x1, float x2, float x3) {
#if HW8
    u32 w = __builtin_amdgcn_cvt_pk_fp8_f32(x0, x1, 0, false);
    w = __builtin_amdgcn_cvt_pk_fp8_f32(x2, x3, w, true);
    return w;
#else
    union { u8 b[4]; u32 u; } p;
    p.b[0] = F8::enc(x0); p.b[1] = F8::enc(x1); p.b[2] = F8::enc(x2); p.b[3] = F8::enc(x3);
    return p.u;
#endif
}
static __device__ inline float4 dec4(u32 v) {
#if HW8
    f32x2 lo = __builtin_amdgcn_cvt_pk_f32_fp8(v, false);
    f32x2 hi = __builtin_amdgcn_cvt_pk_f32_fp8(v, true);
    return make_float4(lo.x, lo.y, hi.x, hi.y);
#else
    union { u32 u; u8 b[4]; } c; c.u = v;
    return make_float4(F8::dec(c.b[0]), F8::dec(c.b[1]), F8::dec(c.b[2]), F8::dec(c.b[3]));
#endif
}
static __device__ inline float dec1(u8 b) {
#if HW8
    return __builtin_amdgcn_cvt_f32_fp8((int)b, 0);
#else
    return F8::dec(b);
#endif
}

// ---------------- degree histograms ----------------
__global__ __launch_bounds__(256) void hist2_k(const int* __restrict__ a, const int* __restrict__ b,
                                               int* __restrict__ ca, int* __restrict__ cb, int n) {
    int i = blockIdx.x * 256 + threadIdx.x;
    if (i < n) { atomicAdd(&ca[a[i]], 1); atomicAdd(&cb[b[i]], 1); }
}
__global__ __launch_bounds__(256) void rs_k(const int* __restrict__ cnt, float* __restrict__ rs, int n) {
    int i = blockIdx.x * 256 + threadIdx.x;
    if (i < n) { int c = cnt[i]; rs[i] = rsqrtf((float)(c < 1 ? 1 : c)); }
}

// ---------------- segment counts of a SORTED id array ----------------
__global__ __launch_bounds__(128) void seg_bounds_k(const int* __restrict__ seg, int n, int B,
                                                    int* __restrict__ cnt) {
    __shared__ int bound[129];
    int b = threadIdx.x;
    if (b <= B) {
        int lo = 0, hi = n;
        while (lo < hi) {
            int mid = (lo + hi) >> 1;
            if (seg[mid] < b) lo = mid + 1; else hi = mid;
        }
        bound[b] = lo;
    }
    __syncthreads();
    if (b < B) cnt[b] = bound[b + 1] - bound[b];
}

// ---------------- scan (exclusive) for CSR offsets ----------------
__global__ __launch_bounds__(256) void scan_block_k(const int* __restrict__ in, int* __restrict__ out,
                                                    int* __restrict__ bsum, int n) {
    __shared__ int sh[256];
    int gid = blockIdx.x * 256 + threadIdx.x;
    int v = (gid < n) ? in[gid] : 0;
    sh[threadIdx.x] = v;
    __syncthreads();
    for (int off = 1; off < 256; off <<= 1) {
        int t = (threadIdx.x >= off) ? sh[threadIdx.x - off] : 0;
        __syncthreads();
        sh[threadIdx.x] += t;
        __syncthreads();
    }
    if (gid < n) out[gid] = sh[threadIdx.x] - v;
    if (threadIdx.x == 255) bsum[blockIdx.x] = sh[255];
}

__global__ __launch_bounds__(256) void scan_bsum_k(int* __restrict__ bsum, int nb) {
    __shared__ int sh[256];
    __shared__ int carry;
    if (threadIdx.x == 0) carry = 0;
    __syncthreads();
    for (int base = 0; base < nb; base += 256) {
        int i = base + threadIdx.x;
        int v = (i < nb) ? bsum[i] : 0;
        sh[threadIdx.x] = v;
        __syncthreads();
        for (int off = 1; off < 256; off <<= 1) {
            int t = (threadIdx.x >= off) ? sh[threadIdx.x - off] : 0;
            __syncthreads();
            sh[threadIdx.x] += t;
            __syncthreads();
        }
        if (i < nb) bsum[i] = sh[threadIdx.x] - v + carry;
        __syncthreads();
        if (threadIdx.x == 0) carry += sh[255];
        __syncthreads();
    }
}

__global__ __launch_bounds__(256) void scan_add_k(int* __restrict__ offs, const int* __restrict__ bsum,
                                                  int* __restrict__ cursor, int n, int nnz) {
    int gid = blockIdx.x * 256 + threadIdx.x;
    if (gid < n) {
        int v = offs[gid] + bsum[gid >> 8];
        offs[gid] = v;
        cursor[gid] = v;
    }
    if (gid == 0) offs[n] = nnz;
}

__global__ __launch_bounds__(256) void fill_csr_k(const int* __restrict__ src, const int* __restrict__ dst,
                                                  int* __restrict__ cursor, int* __restrict__ nbr, int nE) {
    int i = blockIdx.x * 256 + threadIdx.x;
    if (i < nE) {
        int p = atomicAdd(&cursor[dst[i]], 1);
        nbr[p] = src[i];
    }
}

// ---------------- weight prep: Wt[n][k] = (f16) W[k][n] ----------------
__global__ __launch_bounds__(256) void prep_w_k(const float* __restrict__ W, f16* __restrict__ Wt) {
    int idx = blockIdx.x * 256 + threadIdx.x;
    int k = idx >> 7, n = idx & 127;
    Wt[(size_t)n * H + k] = (f16)W[(size_t)k * H + n];
}

// ---------------- feature init (fp8, pre-scaled by rs_out) ----------------
__global__ __launch_bounds__(256) void init_h_k(const int* __restrict__ z, const float* __restrict__ emb,
                                                const float* __restrict__ rs, u8* __restrict__ h, int M) {
    int idx = blockIdx.x * 256 + threadIdx.x;
    if (idx >= M * 32) return;
    int n = idx >> 5, c4 = (idx & 31) << 2;
    float sc = rs[n];
    const float4 v = *(const float4*)(emb + (size_t)z[n] * H + c4);
    *(u32*)(h + (size_t)n * H + c4) = enc4(v.x * sc, v.y * sc, v.z * sc, v.w * sc);
}
__global__ __launch_bounds__(256) void init_e_k(const float* __restrict__ d, const float* __restrict__ epw,
                                                const float* __restrict__ epb, const float* __restrict__ rs,
                                                u8* __restrict__ e, int M) {
    int idx = blockIdx.x * 256 + threadIdx.x;
    if (idx >= M * 32) return;
    int i = idx >> 5, c4 = (idx & 31) << 2;
    float dv = d[i], sc = rs[i];
    const float4 w = *(const float4*)(epw + c4);
    const float4 b = *(const float4*)(epb + c4);
    *(u32*)(e + (size_t)i * H + c4) = enc4(fmaf(dv, w.x, b.x) * sc, fmaf(dv, w.y, b.y) * sc,
                                           fmaf(dv, w.z, b.z) * sc, fmaf(dv, w.w, b.w) * sc);
}

// ---------------- fused conv: gather-agg (LDS) + MFMA GEMM + bias + relu [+rs_out] -> fp8 ----------------
// block = 256 thr (4 waves), 64 dest rows. Phase 1: 8 half-waves gather 8 rows each into
// As[64][136] f16 (fp32 accum, rs folded; X pre-scaled by rs_out). Phase 2: each wave does a
// 16x128 MFMA tile; B-frags from global Wt (L1-hot); epilogue packs fp8.
__global__ __launch_bounds__(256) void conv_fused_k(
    const u8* __restrict__ Xin, u8* __restrict__ Xout,
    const int* __restrict__ offs, const int* __restrict__ nbr,
    const float* __restrict__ rs_in, const f16* __restrict__ Wt,
    const float* __restrict__ bias, const float* __restrict__ scale_out, int M) {
    __shared__ f16 As[64][136];   // row stride 272 B -> 4-bank rotation: 2-way alias on b128 reads (free)

    const int row0 = blockIdx.x * 64;
    const int tid = threadIdx.x;
    const int hw = tid >> 5;      // half-wave 0..7
    const int ln = tid & 31;      // owns cols 4*ln..4*ln+3

    // ---- phase 1: pull-aggregate ----
#pragma unroll
    for (int it = 0; it < 8; ++it) {
        int rl = hw * 8 + it;
        int gr = row0 + rl;
        float a0 = 0.f, a1 = 0.f, a2 = 0.f, a3 = 0.f;
        if (gr < M) {
            int beg = offs[gr], end = offs[gr + 1];
            for (int i = beg; i < end; ++i) {
                int s = nbr[i];
                float4 v = dec4(*(const u32*)(Xin + (size_t)s * H + 4 * ln));
                a0 += v.x; a1 += v.y; a2 += v.z; a3 += v.w;
            }
            float ri = rs_in[gr];
            a0 *= ri; a1 *= ri; a2 *= ri; a3 *= ri;
        }
        union { f16 h[4]; uint2 v; } pk;
        pk.h[0] = (f16)a0; pk.h[1] = (f16)a1; pk.h[2] = (f16)a2; pk.h[3] = (f16)a3;
        *(uint2*)&As[rl][4 * ln] = pk.v;
    }
    __syncthreads();

    // ---- phase 2: MFMA ----
    const int wave = tid >> 6;
    const int lane = tid & 63;
    const int l15 = lane & 15;
    const int quad = lane >> 4;
    const int rowbase = row0 + wave * 16;
    if (rowbase >= M) return;

    f16x8 a[4];
#pragma unroll
    for (int kt = 0; kt < 4; ++kt)
        a[kt] = *(const f16x8*)&As[wave * 16 + l15][kt * 32 + quad * 8];

    // row scales for this lane's 4 output rows (C/D: col=lane&15, row=quad*4+reg)
    float rsc[4];
#pragma unroll
    for (int r = 0; r < 4; ++r) {
        int gr = rowbase + quad * 4 + r;
        rsc[r] = (scale_out && gr < M) ? scale_out[gr] : 1.f;
    }

#pragma unroll
    for (int n0 = 0; n0 < 8; ++n0) {
        f32x4 acc = {0.f, 0.f, 0.f, 0.f};
        const f16* bp = Wt + (size_t)(n0 * 16 + l15) * H + quad * 8;
#pragma unroll
        for (int kt = 0; kt < 4; ++kt) {
            f16x8 b = *(const f16x8*)(bp + kt * 32);
            acc = __builtin_amdgcn_mfma_f32_16x16x32_f16(a[kt], b, acc, 0, 0, 0);
        }
        int col = n0 * 16 + l15;
        float bv = bias[col];
        float o[4];
#pragma unroll
        for (int r = 0; r < 4; ++r) o[r] = fmaxf(acc[r] + bv, 0.f) * rsc[r];
        u32 w = enc4(o[0], o[1], o[2], o[3]);
#pragma unroll
        for (int r = 0; r < 4; ++r) {
            int gr = rowbase + quad * 4 + r;
            if (gr < M) Xout[(size_t)gr * H + col] = (u8)(w >> (8 * r));
        }
    }
}

// ---------------- segment-sum pooling over sorted ids ----------------
__global__ __launch_bounds__(128) void pool_sorted_k(const u8* __restrict__ X, const int* __restrict__ seg,
                                                     float* __restrict__ out_sum, int M) {
    const int chunk = blockIdx.x * 256;
    const int j = threadIdx.x;
    const int end = min(chunk + 256, M);
    float acc = 0.f;
    int g_cur = -1;
    for (int r = chunk; r < end; ++r) {
        int g = seg[r];
        if (g != g_cur) {
            if (g_cur >= 0) atomicAdd(&out_sum[(size_t)g_cur * H + j], acc);
            acc = 0.f;
            g_cur = g;
        }
        acc += dec1(X[(size_t)r * H + j]);
    }
    if (g_cur >= 0) atomicAdd(&out_sum[(size_t)g_cur * H + j], acc);
}

// ---------------- readout MLP ----------------
__global__ __launch_bounds__(128) void readout_k(const float* __restrict__ hg, const float* __restrict__ he,
                                                 const int* __restrict__ cn, const int* __restrict__ ce,
                                                 const float* __restrict__ r1w, const float* __restrict__ r1b,
                                                 const float* __restrict__ r2w, const float* __restrict__ r2b,
                                                 float* __restrict__ out) {
    const int b = blockIdx.x;
    const int j = threadIdx.x;
    const float invn = 1.f / fmaxf((float)cn[b], 1.f);
    const float inve = 1.f / fmaxf((float)ce[b], 1.f);
    float acc = r1b[j];
    for (int k = 0; k < H; ++k) acc = fmaf(hg[(size_t)b * H + k] * invn, r1w[(size_t)k * H + j], acc);
    for (int k = 0; k < H; ++k) acc = fmaf(he[(size_t)b * H + k] * inve, r1w[(size_t)(k + H) * H + j], acc);
    float s = acc / (1.f + expf(-acc));
    __shared__ float red[128];
    red[j] = s * r2w[j];
    __syncthreads();
    for (int off = 64; off > 0; off >>= 1) {
        if (j < off) red[j] += red[j + off];
        __syncthreads();
    }
    if (j == 0) out[b] = red[0] + r2b[0];
}

// diagnostic
__global__ void report_k(float* out, int n, float val) {
    int i = blockIdx.x * 64 + threadIdx.x;
    if (i < n) out[i] = val;
}

extern "C" void kernel_launch(void* const* d_in, const int* in_sizes, int n_in,
                              void* d_out, int out_size, void* d_ws, size_t ws_size,
                              hipStream_t stream) {
    const int* z          = (const int*)d_in[0];
    const float* d        = (const float*)d_in[1];
    const int* src        = (const int*)d_in[2];
    const int* dst        = (const int*)d_in[3];
    const int* lsrc       = (const int*)d_in[4];
    const int* ldst       = (const int*)d_in[5];
    const int* node_graph = (const int*)d_in[6];
    const int* edge_graph = (const int*)d_in[7];
    const float* emb      = (const float*)d_in[8];
    const float* epw      = (const float*)d_in[9];
    const float* epb      = (const float*)d_in[10];
    const float* gW       = (const float*)d_in[11];
    const float* gb       = (const float*)d_in[12];
    const float* lgW      = (const float*)d_in[13];
    const float* lgb      = (const float*)d_in[14];
    const float* r1w      = (const float*)d_in[15];
    const float* r1b      = (const float*)d_in[16];
    const float* r2w      = (const float*)d_in[17];
    const float* r2b      = (const float*)d_in[18];

    const int N  = in_sizes[0];
    const int E  = in_sizes[2];
    const int E2 = in_sizes[4];
    const int B  = out_size;
    const int L  = 3;
    float* out = (float*)d_out;
    char* ws = (char*)d_ws;

    // ---- workspace (~195 MB; budget 268 MB) ----
    size_t off = 0;
    auto al = [&](size_t b) -> char* { char* q = ws + off; off += (b + 255) & ~(size_t)255; return q; };
    u8*  featA = (u8*)al((size_t)E * H);             // 76.8 MB fp8 (pre-scaled by rs_out)
    u8*  featB = (u8*)al((size_t)E * H);             // 76.8 MB ping-pong
    f16* wt    = (f16*)al((size_t)2 * L * H * H * 2);
    float* ron = (float*)al((size_t)N * 4);
    float* rin = (float*)al((size_t)N * 4);
    float* roe = (float*)al((size_t)E * 4);
    float* rie = (float*)al((size_t)E * 4);
    size_t cntCount = (size_t)2 * N + 2 * E + 2 * B;
    int* cnts = (int*)al(cntCount * 4);
    size_t cntBytes = ((size_t)2 * N + 2 * E) * 4;
    int* con = cnts; int* cin_ = con + N; int* coe = cin_ + N; int* cie = coe + E;
    int* cntn = cie + E; int* cnte = cntn + B;
    int* offs_n = (int*)al(((size_t)N + 1) * 4);
    int* cur_n  = (int*)al((size_t)N * 4);
    int* offs_e = (int*)al(((size_t)E + 1) * 4);
    int* cur_e  = (int*)al((size_t)E * 4);
    int* nbr_n  = (int*)al((size_t)E * 4);
    int* nbr_e  = (int*)al((size_t)E2 * 4);
    int* bsum   = (int*)al(((size_t)cdiv(E > N ? E : N, 256) + 1) * 4);
    float* pools = (float*)al((size_t)2 * B * H * 4);
    float* hg = pools;
    float* he = pools + (size_t)B * H;

    if (off > ws_size) {
        report_k<<<cdiv(B, 64), 64, 0, stream>>>(out, B, (float)(ws_size >> 20));
        return;
    }

    hipMemsetAsync(cnts, 0, cntBytes, stream);
    hipMemsetAsync(pools, 0, (size_t)2 * B * H * 4, stream);

    // weight prep (6 layers)
    for (int l = 0; l < L; ++l) {
        prep_w_k<<<64, 256, 0, stream>>>(gW + (size_t)l * H * H, wt + (size_t)l * H * H);
        prep_w_k<<<64, 256, 0, stream>>>(lgW + (size_t)l * H * H, wt + (size_t)(L + l) * H * H);
    }

    // degrees + graph-segment counts
    hist2_k<<<cdiv(E, 256), 256, 0, stream>>>(src, dst, con, cin_, E);
    hist2_k<<<cdiv(E2, 256), 256, 0, stream>>>(lsrc, ldst, coe, cie, E2);
    seg_bounds_k<<<1, 128, 0, stream>>>(node_graph, N, B, cntn);
    seg_bounds_k<<<1, 128, 0, stream>>>(edge_graph, E, B, cnte);
    rs_k<<<cdiv(N, 256), 256, 0, stream>>>(con, ron, N);
    rs_k<<<cdiv(N, 256), 256, 0, stream>>>(cin_, rin, N);
    rs_k<<<cdiv(E, 256), 256, 0, stream>>>(coe, roe, E);
    rs_k<<<cdiv(E, 256), 256, 0, stream>>>(cie, rie, E);

    // CSR (by dst) for both graphs
    int nbN = cdiv(N, 256), nbE = cdiv(E, 256);
    scan_block_k<<<nbN, 256, 0, stream>>>(cin_, offs_n, bsum, N);
    scan_bsum_k<<<1, 256, 0, stream>>>(bsum, nbN);
    scan_add_k<<<nbN, 256, 0, stream>>>(offs_n, bsum, cur_n, N, E);
    fill_csr_k<<<cdiv(E, 256), 256, 0, stream>>>(src, dst, cur_n, nbr_n, E);

    scan_block_k<<<nbE, 256, 0, stream>>>(cie, offs_e, bsum, E);
    scan_bsum_k<<<1, 256, 0, stream>>>(bsum, nbE);
    scan_add_k<<<nbE, 256, 0, stream>>>(offs_e, bsum, cur_e, E, E2);
    fill_csr_k<<<cdiv(E2, 256), 256, 0, stream>>>(lsrc, ldst, cur_e, nbr_e, E2);

    // node-graph phase
    init_h_k<<<cdiv((long long)N * 32, 256), 256, 0, stream>>>(z, emb, ron, featA, N);
    u8* cur = featA;
    for (int l = 0; l < L; ++l) {
        u8* nxt = (cur == featA) ? featB : featA;
        conv_fused_k<<<cdiv(N, 64), 256, 0, stream>>>(cur, nxt, offs_n, nbr_n, rin,
                                                      wt + (size_t)l * H * H, gb + (size_t)l * H,
                                                      (l < L - 1) ? ron : nullptr, N);
        cur = nxt;
    }
    pool_sorted_k<<<cdiv(N, 256), 128, 0, stream>>>(cur, node_graph, hg, N);

    // line-graph phase
    init_e_k<<<cdiv((long long)E * 32, 256), 256, 0, stream>>>(d, epw, epb, roe, featA, E);
    cur = featA;
    for (int l = 0; l < L; ++l) {
        u8* nxt = (cur == featA) ? featB : featA;
        conv_fused_k<<<cdiv(E, 64), 256, 0, stream>>>(cur, nxt, offs_e, nbr_e, rie,
                                                      wt + (size_t)(L + l) * H * H, lgb + (size_t)l * H,
                                                      (l < L - 1) ? roe : nullptr, E);
        cur = nxt;
    }
    pool_sorted_k<<<cdiv(E, 256), 128, 0, stream>>>(cur, edge_graph, he, E);

    readout_k<<<B, 128, 0, stream>>>(hg, he, cntn, cnte, r1w, r1b, r2w, r2b, out);
}

// Round 8
// 1412.872 us; speedup vs baseline: 5.5687x; 1.1441x over previous
//
#include <hip/hip_runtime.h>
#include <math.h>

#define H 128
typedef unsigned short u16;
typedef unsigned char u8;
typedef unsigned int u32;
typedef _Float16 f16;
typedef f16 f16x8 __attribute__((ext_vector_type(8)));
typedef float f32x4 __attribute__((ext_vector_type(4)));
typedef float f32x2 __attribute__((ext_vector_type(2)));

#if __has_builtin(__builtin_amdgcn_cvt_pk_fp8_f32)
#define HW8 1
#else
#define HW8 0
#endif

static inline int cdiv(long long a, long long b) { return (int)((a + b - 1) / b); }

// ---------------- fp8 e4m3fn software codec (fallback) ----------------
struct F8 {
    static __device__ inline float dec(u8 v) {
        int e = (v >> 3) & 15, m = v & 7;
        float f = (e == 0) ? (float)m * 0.001953125f : ldexpf(1.f + 0.125f * (float)m, e - 7);
        return (v & 0x80) ? -f : f;
    }
    static __device__ inline u8 enc(float x) {
        u8 s = (u8)((__float_as_uint(x) >> 24) & 0x80);
        float ax = fabsf(x);
        if (!(ax < 448.f)) return s | 0x7E;
        if (ax < 0.015625f) {
            int m = (int)rintf(ax * 512.f);
            if (m >= 8) return s | 0x08;
            return s | (u8)m;
        }
        int e; float fr = frexpf(ax, &e);
        int E = e - 1;
        int m = (int)rintf(fr * 16.f - 8.f);
        if (m == 8) { m = 0; ++E; }
        if (E > 8) return s | 0x7E;
        return s | (u8)(((E + 7) << 3) | m);
    }
};

static __device__ inline u32 enc4(float x0, float x1, float x2, float x3) {
#if HW8
    u32 w = __builtin_amdgcn_cvt_pk_fp8_f32(x0, x1, 0, false);
    w = __builtin_amdgcn_cvt_pk_fp8_f32(x2, x3, w, true);
    return w;
#else
    union { u8 b[4]; u32 u; } p;
    p.b[0] = F8::enc(x0); p.b[1] = F8::enc(x1); p.b[2] = F8::enc(x2); p.b[3] = F8::enc(x3);
    return p.u;
#endif
}
static __device__ inline float4 dec4(u32 v) {
#if HW8
    f32x2 lo = __builtin_amdgcn_cvt_pk_f32_fp8(v, false);
    f32x2 hi = __builtin_amdgcn_cvt_pk_f32_fp8(v, true);
    return make_float4(lo.x, lo.y, hi.x, hi.y);
#else
    union { u32 u; u8 b[4]; } c; c.u = v;
    return make_float4(F8::dec(c.b[0]), F8::dec(c.b[1]), F8::dec(c.b[2]), F8::dec(c.b[3]));
#endif
}
static __device__ inline float dec1(u8 b) {
#if HW8
    return __builtin_amdgcn_cvt_f32_fp8((int)b, 0);
#else
    return F8::dec(b);
#endif
}

// ---------------- degree histograms ----------------
__global__ __launch_bounds__(256) void hist2_k(const int* __restrict__ a, const int* __restrict__ b,
                                               int* __restrict__ ca, int* __restrict__ cb, int n) {
    int i = blockIdx.x * 256 + threadIdx.x;
    if (i < n) { atomicAdd(&ca[a[i]], 1); atomicAdd(&cb[b[i]], 1); }
}
__global__ __launch_bounds__(256) void rs_k(const int* __restrict__ cnt, float* __restrict__ rs, int n) {
    int i = blockIdx.x * 256 + threadIdx.x;
    if (i < n) { int c = cnt[i]; rs[i] = rsqrtf((float)(c < 1 ? 1 : c)); }
}

// ---------------- segment counts of a SORTED id array ----------------
__global__ __launch_bounds__(128) void seg_bounds_k(const int* __restrict__ seg, int n, int B,
                                                    int* __restrict__ cnt) {
    __shared__ int bound[129];
    int b = threadIdx.x;
    if (b <= B) {
        int lo = 0, hi = n;
        while (lo < hi) {
            int mid = (lo + hi) >> 1;
            if (seg[mid] < b) lo = mid + 1; else hi = mid;
        }
        bound[b] = lo;
    }
    __syncthreads();
    if (b < B) cnt[b] = bound[b + 1] - bound[b];
}

// ---------------- scan (exclusive) for CSR offsets ----------------
__global__ __launch_bounds__(256) void scan_block_k(const int* __restrict__ in, int* __restrict__ out,
                                                    int* __restrict__ bsum, int n) {
    __shared__ int sh[256];
    int gid = blockIdx.x * 256 + threadIdx.x;
    int v = (gid < n) ? in[gid] : 0;
    sh[threadIdx.x] = v;
    __syncthreads();
    for (int off = 1; off < 256; off <<= 1) {
        int t = (threadIdx.x >= off) ? sh[threadIdx.x - off] : 0;
        __syncthreads();
        sh[threadIdx.x] += t;
        __syncthreads();
    }
    if (gid < n) out[gid] = sh[threadIdx.x] - v;
    if (threadIdx.x == 255) bsum[blockIdx.x] = sh[255];
}

__global__ __launch_bounds__(256) void scan_bsum_k(int* __restrict__ bsum, int nb) {
    __shared__ int sh[256];
    __shared__ int carry;
    if (threadIdx.x == 0) carry = 0;
    __syncthreads();
    for (int base = 0; base < nb; base += 256) {
        int i = base + threadIdx.x;
        int v = (i < nb) ? bsum[i] : 0;
        sh[threadIdx.x] = v;
        __syncthreads();
        for (int off = 1; off < 256; off <<= 1) {
            int t = (threadIdx.x >= off) ? sh[threadIdx.x - off] : 0;
            __syncthreads();
            sh[threadIdx.x] += t;
            __syncthreads();
        }
        if (i < nb) bsum[i] = sh[threadIdx.x] - v + carry;
        __syncthreads();
        if (threadIdx.x == 0) carry += sh[255];
        __syncthreads();
    }
}

__global__ __launch_bounds__(256) void scan_add_k(int* __restrict__ offs, const int* __restrict__ bsum,
                                                  int* __restrict__ cursor, int n, int nnz) {
    int gid = blockIdx.x * 256 + threadIdx.x;
    if (gid < n) {
        int v = offs[gid] + bsum[gid >> 8];
        offs[gid] = v;
        cursor[gid] = v;
    }
    if (gid == 0) offs[n] = nnz;
}

__global__ __launch_bounds__(256) void fill_csr_k(const int* __restrict__ src, const int* __restrict__ dst,
                                                  int* __restrict__ cursor, int* __restrict__ nbr, int nE) {
    int i = blockIdx.x * 256 + threadIdx.x;
    if (i < nE) {
        int p = atomicAdd(&cursor[dst[i]], 1);
        nbr[p] = src[i];
    }
}

// ---------------- weight prep: Wt[n][k] = (f16) W[k][n] ----------------
__global__ __launch_bounds__(256) void prep_w_k(const float* __restrict__ W, f16* __restrict__ Wt) {
    int idx = blockIdx.x * 256 + threadIdx.x;
    int k = idx >> 7, n = idx & 127;
    Wt[(size_t)n * H + k] = (f16)W[(size_t)k * H + n];
}

// ---------------- feature init (fp8, pre-scaled by rs_out) ----------------
__global__ __launch_bounds__(256) void init_h_k(const int* __restrict__ z, const float* __restrict__ emb,
                                                const float* __restrict__ rs, u8* __restrict__ h, int M) {
    int idx = blockIdx.x * 256 + threadIdx.x;
    if (idx >= M * 32) return;
    int n = idx >> 5, c4 = (idx & 31) << 2;
    float sc = rs[n];
    const float4 v = *(const float4*)(emb + (size_t)z[n] * H + c4);
    *(u32*)(h + (size_t)n * H + c4) = enc4(v.x * sc, v.y * sc, v.z * sc, v.w * sc);
}
__global__ __launch_bounds__(256) void init_e_k(const float* __restrict__ d, const float* __restrict__ epw,
                                                const float* __restrict__ epb, const float* __restrict__ rs,
                                                u8* __restrict__ e, int M) {
    int idx = blockIdx.x * 256 + threadIdx.x;
    if (idx >= M * 32) return;
    int i = idx >> 5, c4 = (idx & 31) << 2;
    float dv = d[i], sc = rs[i];
    const float4 w = *(const float4*)(epw + c4);
    const float4 b = *(const float4*)(epb + c4);
    *(u32*)(e + (size_t)i * H + c4) = enc4(fmaf(dv, w.x, b.x) * sc, fmaf(dv, w.y, b.y) * sc,
                                           fmaf(dv, w.z, b.z) * sc, fmaf(dv, w.w, b.w) * sc);
}

// ---------------- fused conv: flattened-gather (LDS) + MFMA GEMM + bias + relu [+rs_out] -> fp8 ----------------
// block = 256 thr (4 waves), 64 dest rows.
// Phase 1: each half-wave owns 8 consecutive rows; their CSR edge lists are CONTIGUOUS, so we
// iterate the flattened edge range 4 at a time: 4 nbr loads issue together, 4 feature loads issue
// together (4x memory-level parallelism vs serial per-row chains), then distribute into the per-row
// accumulator using the register boundary array (rows owned exclusively -> no atomics; per-row
// accumulation order unchanged -> bitwise-identical to round 7).
// Phase 2: per-wave 16x128 MFMA tile; B-frags from global Wt (L1-hot).
__global__ __launch_bounds__(256) void conv_fused_k(
    const u8* __restrict__ Xin, u8* __restrict__ Xout,
    const int* __restrict__ offs, const int* __restrict__ nbr,
    const float* __restrict__ rs_in, const f16* __restrict__ Wt,
    const float* __restrict__ bias, const float* __restrict__ scale_out, int M) {
    __shared__ f16 As[64][136];   // row stride 272 B -> 2-way bank alias on b128 reads (free)

    const int row0 = blockIdx.x * 64;
    const int tid = threadIdx.x;
    const int hw = tid >> 5;      // half-wave 0..7
    const int ln = tid & 31;      // owns cols 4*ln..4*ln+3

    // ---- phase 1: flattened pull-aggregate over 8 owned rows ----
    {
        const int r0l = hw * 8;            // local row base
        const int gr0 = row0 + r0l;        // global row base
        int b[9];
#pragma unroll
        for (int k = 0; k < 9; ++k) {
            int idx = gr0 + k;
            if (idx > M) idx = M;
            b[k] = offs[idx];
        }
        float a0 = 0.f, a1 = 0.f, a2 = 0.f, a3 = 0.f;
        int cur = 0;
        const int jend = b[8];
        for (int j = b[0]; j < jend; j += 4) {
            // issue all index loads, then all feature loads (4x MLP)
            int s0, s1, s2, s3;
            {
                int j1 = j + 1 < jend ? j + 1 : jend - 1;
                int j2 = j + 2 < jend ? j + 2 : jend - 1;
                int j3 = j + 3 < jend ? j + 3 : jend - 1;
                s0 = nbr[j]; s1 = nbr[j1]; s2 = nbr[j2]; s3 = nbr[j3];
            }
            u32 w0 = *(const u32*)(Xin + (size_t)s0 * H + 4 * ln);
            u32 w1 = *(const u32*)(Xin + (size_t)s1 * H + 4 * ln);
            u32 w2 = *(const u32*)(Xin + (size_t)s2 * H + 4 * ln);
            u32 w3 = *(const u32*)(Xin + (size_t)s3 * H + 4 * ln);
            u32 wv[4] = {w0, w1, w2, w3};
#pragma unroll
            for (int k = 0; k < 4; ++k) {
                int jj = j + k;
                if (jj < jend) {
                    while (jj >= b[cur + 1]) {   // row finished: flush accumulator
                        float ri = (gr0 + cur < M) ? rs_in[gr0 + cur] : 0.f;
                        union { f16 h[4]; uint2 v; } pk;
                        pk.h[0] = (f16)(a0 * ri); pk.h[1] = (f16)(a1 * ri);
                        pk.h[2] = (f16)(a2 * ri); pk.h[3] = (f16)(a3 * ri);
                        *(uint2*)&As[r0l + cur][4 * ln] = pk.v;
                        a0 = a1 = a2 = a3 = 0.f;
                        ++cur;
                    }
                    float4 v = dec4(wv[k]);
                    a0 += v.x; a1 += v.y; a2 += v.z; a3 += v.w;
                }
            }
        }
        while (cur < 8) {                    // flush remaining (incl. empty/padding rows)
            float ri = (gr0 + cur < M) ? rs_in[gr0 + cur] : 0.f;
            union { f16 h[4]; uint2 v; } pk;
            pk.h[0] = (f16)(a0 * ri); pk.h[1] = (f16)(a1 * ri);
            pk.h[2] = (f16)(a2 * ri); pk.h[3] = (f16)(a3 * ri);
            *(uint2*)&As[r0l + cur][4 * ln] = pk.v;
            a0 = a1 = a2 = a3 = 0.f;
            ++cur;
        }
    }
    __syncthreads();

    // ---- phase 2: MFMA ----
    const int wave = tid >> 6;
    const int lane = tid & 63;
    const int l15 = lane & 15;
    const int quad = lane >> 4;
    const int rowbase = row0 + wave * 16;
    if (rowbase >= M) return;

    f16x8 a[4];
#pragma unroll
    for (int kt = 0; kt < 4; ++kt)
        a[kt] = *(const f16x8*)&As[wave * 16 + l15][kt * 32 + quad * 8];

    // row scales for this lane's 4 output rows (C/D: col=lane&15, row=quad*4+reg)
    float rsc[4];
#pragma unroll
    for (int r = 0; r < 4; ++r) {
        int gr = rowbase + quad * 4 + r;
        rsc[r] = (scale_out && gr < M) ? scale_out[gr] : 1.f;
    }

#pragma unroll
    for (int n0 = 0; n0 < 8; ++n0) {
        f32x4 acc = {0.f, 0.f, 0.f, 0.f};
        const f16* bp = Wt + (size_t)(n0 * 16 + l15) * H + quad * 8;
#pragma unroll
        for (int kt = 0; kt < 4; ++kt) {
            f16x8 b = *(const f16x8*)(bp + kt * 32);
            acc = __builtin_amdgcn_mfma_f32_16x16x32_f16(a[kt], b, acc, 0, 0, 0);
        }
        int col = n0 * 16 + l15;
        float bv = bias[col];
        float o[4];
#pragma unroll
        for (int r = 0; r < 4; ++r) o[r] = fmaxf(acc[r] + bv, 0.f) * rsc[r];
        u32 w = enc4(o[0], o[1], o[2], o[3]);
#pragma unroll
        for (int r = 0; r < 4; ++r) {
            int gr = rowbase + quad * 4 + r;
            if (gr < M) Xout[(size_t)gr * H + col] = (u8)(w >> (8 * r));
        }
    }
}

// ---------------- segment-sum pooling over sorted ids ----------------
__global__ __launch_bounds__(128) void pool_sorted_k(const u8* __restrict__ X, const int* __restrict__ seg,
                                                     float* __restrict__ out_sum, int M) {
    const int chunk = blockIdx.x * 256;
    const int j = threadIdx.x;
    const int end = min(chunk + 256, M);
    float acc = 0.f;
    int g_cur = -1;
    for (int r = chunk; r < end; ++r) {
        int g = seg[r];
        if (g != g_cur) {
            if (g_cur >= 0) atomicAdd(&out_sum[(size_t)g_cur * H + j], acc);
            acc = 0.f;
            g_cur = g;
        }
        acc += dec1(X[(size_t)r * H + j]);
    }
    if (g_cur >= 0) atomicAdd(&out_sum[(size_t)g_cur * H + j], acc);
}

// ---------------- readout MLP ----------------
__global__ __launch_bounds__(128) void readout_k(const float* __restrict__ hg, const float* __restrict__ he,
                                                 const int* __restrict__ cn, const int* __restrict__ ce,
                                                 const float* __restrict__ r1w, const float* __restrict__ r1b,
                                                 const float* __restrict__ r2w, const float* __restrict__ r2b,
                                                 float* __restrict__ out) {
    const int b = blockIdx.x;
    const int j = threadIdx.x;
    const float invn = 1.f / fmaxf((float)cn[b], 1.f);
    const float inve = 1.f / fmaxf((float)ce[b], 1.f);
    float acc = r1b[j];
    for (int k = 0; k < H; ++k) acc = fmaf(hg[(size_t)b * H + k] * invn, r1w[(size_t)k * H + j], acc);
    for (int k = 0; k < H; ++k) acc = fmaf(he[(size_t)b * H + k] * inve, r1w[(size_t)(k + H) * H + j], acc);
    float s = acc / (1.f + expf(-acc));
    __shared__ float red[128];
    red[j] = s * r2w[j];
    __syncthreads();
    for (int off = 64; off > 0; off >>= 1) {
        if (j < off) red[j] += red[j + off];
        __syncthreads();
    }
    if (j == 0) out[b] = red[0] + r2b[0];
}

// diagnostic
__global__ void report_k(float* out, int n, float val) {
    int i = blockIdx.x * 64 + threadIdx.x;
    if (i < n) out[i] = val;
}

extern "C" void kernel_launch(void* const* d_in, const int* in_sizes, int n_in,
                              void* d_out, int out_size, void* d_ws, size_t ws_size,
                              hipStream_t stream) {
    const int* z          = (const int*)d_in[0];
    const float* d        = (const float*)d_in[1];
    const int* src        = (const int*)d_in[2];
    const int* dst        = (const int*)d_in[3];
    const int* lsrc       = (const int*)d_in[4];
    const int* ldst       = (const int*)d_in[5];
    const int* node_graph = (const int*)d_in[6];
    const int* edge_graph = (const int*)d_in[7];
    const float* emb      = (const float*)d_in[8];
    const float* epw      = (const float*)d_in[9];
    const float* epb      = (const float*)d_in[10];
    const float* gW       = (const float*)d_in[11];
    const float* gb       = (const float*)d_in[12];
    const float* lgW      = (const float*)d_in[13];
    const float* lgb      = (const float*)d_in[14];
    const float* r1w      = (const float*)d_in[15];
    const float* r1b      = (const float*)d_in[16];
    const float* r2w      = (const float*)d_in[17];
    const float* r2b      = (const float*)d_in[18];

    const int N  = in_sizes[0];
    const int E  = in_sizes[2];
    const int E2 = in_sizes[4];
    const int B  = out_size;
    const int L  = 3;
    float* out = (float*)d_out;
    char* ws = (char*)d_ws;

    // ---- workspace (~195 MB; budget 268 MB) ----
    size_t off = 0;
    auto al = [&](size_t b) -> char* { char* q = ws + off; off += (b + 255) & ~(size_t)255; return q; };
    u8*  featA = (u8*)al((size_t)E * H);             // 76.8 MB fp8 (pre-scaled by rs_out)
    u8*  featB = (u8*)al((size_t)E * H);             // 76.8 MB ping-pong
    f16* wt    = (f16*)al((size_t)2 * L * H * H * 2);
    float* ron = (float*)al((size_t)N * 4);
    float* rin = (float*)al((size_t)N * 4);
    float* roe = (float*)al((size_t)E * 4);
    float* rie = (float*)al((size_t)E * 4);
    size_t cntCount = (size_t)2 * N + 2 * E + 2 * B;
    int* cnts = (int*)al(cntCount * 4);
    size_t cntBytes = ((size_t)2 * N + 2 * E) * 4;
    int* con = cnts; int* cin_ = con + N; int* coe = cin_ + N; int* cie = coe + E;
    int* cntn = cie + E; int* cnte = cntn + B;
    int* offs_n = (int*)al(((size_t)N + 1) * 4);
    int* cur_n  = (int*)al((size_t)N * 4);
    int* offs_e = (int*)al(((size_t)E + 1) * 4);
    int* cur_e  = (int*)al((size_t)E * 4);
    int* nbr_n  = (int*)al((size_t)E * 4);
    int* nbr_e  = (int*)al((size_t)E2 * 4);
    int* bsum   = (int*)al(((size_t)cdiv(E > N ? E : N, 256) + 1) * 4);
    float* pools = (float*)al((size_t)2 * B * H * 4);
    float* hg = pools;
    float* he = pools + (size_t)B * H;

    if (off > ws_size) {
        report_k<<<cdiv(B, 64), 64, 0, stream>>>(out, B, (float)(ws_size >> 20));
        return;
    }

    hipMemsetAsync(cnts, 0, cntBytes, stream);
    hipMemsetAsync(pools, 0, (size_t)2 * B * H * 4, stream);

    // weight prep (6 layers)
    for (int l = 0; l < L; ++l) {
        prep_w_k<<<64, 256, 0, stream>>>(gW + (size_t)l * H * H, wt + (size_t)l * H * H);
        prep_w_k<<<64, 256, 0, stream>>>(lgW + (size_t)l * H * H, wt + (size_t)(L + l) * H * H);
    }

    // degrees + graph-segment counts
    hist2_k<<<cdiv(E, 256), 256, 0, stream>>>(src, dst, con, cin_, E);
    hist2_k<<<cdiv(E2, 256), 256, 0, stream>>>(lsrc, ldst, coe, cie, E2);
    seg_bounds_k<<<1, 128, 0, stream>>>(node_graph, N, B, cntn);
    seg_bounds_k<<<1, 128, 0, stream>>>(edge_graph, E, B, cnte);
    rs_k<<<cdiv(N, 256), 256, 0, stream>>>(con, ron, N);
    rs_k<<<cdiv(N, 256), 256, 0, stream>>>(cin_, rin, N);
    rs_k<<<cdiv(E, 256), 256, 0, stream>>>(coe, roe, E);
    rs_k<<<cdiv(E, 256), 256, 0, stream>>>(cie, rie, E);

    // CSR (by dst) for both graphs
    int nbN = cdiv(N, 256), nbE = cdiv(E, 256);
    scan_block_k<<<nbN, 256, 0, stream>>>(cin_, offs_n, bsum, N);
    scan_bsum_k<<<1, 256, 0, stream>>>(bsum, nbN);
    scan_add_k<<<nbN, 256, 0, stream>>>(offs_n, bsum, cur_n, N, E);
    fill_csr_k<<<cdiv(E, 256), 256, 0, stream>>>(src, dst, cur_n, nbr_n, E);

    scan_block_k<<<nbE, 256, 0, stream>>>(cie, offs_e, bsum, E);
    scan_bsum_k<<<1, 256, 0, stream>>>(bsum, nbE);
    scan_add_k<<<nbE, 256, 0, stream>>>(offs_e, bsum, cur_e, E, E2);
    fill_csr_k<<<cdiv(E2, 256), 256, 0, stream>>>(lsrc, ldst, cur_e, nbr_e, E2);

    // node-graph phase
    init_h_k<<<cdiv((long long)N * 32, 256), 256, 0, stream>>>(z, emb, ron, featA, N);
    u8* cur = featA;
    for (int l = 0; l < L; ++l) {
        u8* nxt = (cur == featA) ? featB : featA;
        conv_fused_k<<<cdiv(N, 64), 256, 0, stream>>>(cur, nxt, offs_n, nbr_n, rin,
                                                      wt + (size_t)l * H * H, gb + (size_t)l * H,
                                                      (l < L - 1) ? ron : nullptr, N);
        cur = nxt;
    }
    pool_sorted_k<<<cdiv(N, 256), 128, 0, stream>>>(cur, node_graph, hg, N);

    // line-graph phase
    init_e_k<<<cdiv((long long)E * 32, 256), 256, 0, stream>>>(d, epw, epb, roe, featA, E);
    cur = featA;
    for (int l = 0; l < L; ++l) {
        u8* nxt = (cur == featA) ? featB : featA;
        conv_fused_k<<<cdiv(E, 64), 256, 0, stream>>>(cur, nxt, offs_e, nbr_e, rie,
                                                      wt + (size_t)(L + l) * H * H, lgb + (size_t)l * H,
                                                      (l < L - 1) ? roe : nullptr, E);
        cur = nxt;
    }
    pool_sorted_k<<<cdiv(E, 256), 128, 0, stream>>>(cur, edge_graph, he, E);

    readout_k<<<B, 128, 0, stream>>>(hg, he, cntn, cnte, r1w, r1b, r2w, r2b, out);
}